// Round 17
// baseline (344.401 us; speedup 1.0000x reference)
//
#include <hip/hip_runtime.h>
#include <math.h>

#define BB 2
#define NN 8192
#define NPTS (BB*NN)

typedef unsigned long long u64;
typedef short s16;
typedef __attribute__((ext_vector_type(8))) short short8v;
typedef __attribute__((ext_vector_type(4))) float f32x4;

__device__ __forceinline__ unsigned short f2bf(float v){
  unsigned u = __float_as_uint(v);
  return (unsigned short)((u + 0x7FFFu + ((u >> 16) & 1u)) >> 16);
}
__device__ __forceinline__ float bf2f(unsigned short h){
  return __uint_as_float(((unsigned)h) << 16);
}

// ---------------- zero init (g2/g3 atomic-max targets) ----------------
__global__ __launch_bounds__(256) void zero_kernel(float* p, int n){
  int i = blockIdx.x*256 + threadIdx.x;
  if (i < n) p[i] = 0.f;
}

// ---------------- pts -> float4 pad with |q|^2 in w (aliases dead ftr1 region) ----------------
__global__ __launch_bounds__(256) void pad4_kernel(const float* __restrict__ pts, float4* __restrict__ pts4){
  int i = blockIdx.x*256 + threadIdx.x;
  if (i < NPTS){
    float x = pts[(size_t)i*3], y = pts[(size_t)i*3+1], z = pts[(size_t)i*3+2];
    pts4[i] = make_float4(x, y, z, x*x + y*y + z*z);
  }
}

// ---------------- KNN helpers: f32 branchless bitonic primitives (validated) ----------------
__device__ __forceinline__ void fce(float& a, float& b){
  float lo = fminf(a, b), hi = fmaxf(a, b);
  a = lo; b = hi;
}

__device__ __forceinline__ void bclean16f(float e[16]){
  #pragma unroll
  for (int i=0;i<8;++i) fce(e[i], e[i+8]);
  #pragma unroll
  for (int g=0; g<2; ++g){
    #pragma unroll
    for (int i=0;i<4;++i) fce(e[g*8+i], e[g*8+i+4]);
  }
  #pragma unroll
  for (int g=0; g<4; ++g){
    #pragma unroll
    for (int i=0;i<2;++i) fce(e[g*4+i], e[g*4+i+2]);
  }
  #pragma unroll
  for (int g=0; g<8; ++g) fce(e[g*2], e[g*2+1]);
}

__device__ __forceinline__ void clean8f(float A[8]){
  fce(A[0],A[4]); fce(A[1],A[5]); fce(A[2],A[6]); fce(A[3],A[7]);
  fce(A[0],A[2]); fce(A[1],A[3]); fce(A[4],A[6]); fce(A[5],A[7]);
  fce(A[0],A[1]); fce(A[2],A[3]); fce(A[4],A[5]); fce(A[6],A[7]);
}

__device__ __forceinline__ void merge_keep16f(float e[16], int maskXor){
  float p[16];
  #pragma unroll
  for (int i=0;i<16;++i) p[i] = __shfl_xor(e[i], maskXor);
  #pragma unroll
  for (int i=0;i<16;++i){ float o = p[15-i]; e[i] = fminf(e[i], o); }
  bclean16f(e);
}

// ---- KNN v8: expanded-form distance (3 FMA), register-cached scan, f32 threshold,
//      count-verified collection. d' = |q|^2 - 2 p.q  (ordering == true distance) ----
__global__ __launch_bounds__(256) void knn_kernel(const float* __restrict__ pts,
                                                  const float4* __restrict__ pts4,
                                                  int* __restrict__ knn){
  __shared__ float poold[1024];           // [slot 0..15][col 0..63]
  __shared__ float ldsT;
  __shared__ int   cnt;
  __shared__ int   list[16];
  const int tid  = threadIdx.x;
  const int wid  = tid >> 6;
  const int lane = tid & 63;
  const int point = blockIdx.x;
  const int b = point >> 13;
  const int n = point & (NN-1);
  const float4* pb4 = pts4 + (size_t)b*NN;
  const float4 self = pb4[n];
  const float m2x = -2.f*self.x, m2y = -2.f*self.y, m2z = -2.f*self.z;

  // scan 1: per-lane top-4 of d' (med3 sorted-insert), d' register-cached
  float dcache[32];
  float d0=INFINITY, d1=INFINITY, d2=INFINITY, d3=INFINITY;
  const int mbase = wid*2048 + lane;
  #pragma unroll
  for (int t = 0; t < 32; ++t){
    int m = mbase + t*64;
    float4 q = pb4[m];
    float dist = fmaf(q.x, m2x, fmaf(q.y, m2y, fmaf(q.z, m2z, q.w)));
    dist = (m == n) ? INFINITY : dist;    // exclude self (stays excluded in scan 2)
    dcache[t] = dist;
    float n3 = __builtin_amdgcn_fmed3f(dist, d2, d3);
    float n2 = __builtin_amdgcn_fmed3f(dist, d1, d2);
    float n1 = __builtin_amdgcn_fmed3f(dist, d0, d1);
    float n0 = fminf(dist, d0);
    d3=n3; d2=n2; d1=n1; d0=n0;
  }

  // pool: thread t=(col=t>>2, j=t&3) writes sorted-4 run to slots j*4..j*4+3, column col
  {
    const int j = tid & 3, col = tid >> 2;
    poold[(j*4+0)*64 + col] = d0;
    poold[(j*4+1)*64 + col] = d1;
    poold[(j*4+2)*64 + col] = d2;
    poold[(j*4+3)*64 + col] = d3;
  }
  if (tid == 0) cnt = 0;
  __syncthreads();

  // wave 0: f32 selection network (validated) -> T = pooled 16th-smallest d'
  if (wid == 0){
    float r[16];
    #pragma unroll
    for (int s=0;s<16;++s) r[s] = poold[s*64 + lane];
    float A[8] = {r[0],r[1],r[2],r[3],r[7],r[6],r[5],r[4]};
    clean8f(A);
    float B[8] = {r[8],r[9],r[10],r[11],r[15],r[14],r[13],r[12]};
    clean8f(B);
    float e[16];
    e[0]=A[0]; e[1]=A[1]; e[2]=A[2]; e[3]=A[3]; e[4]=A[4]; e[5]=A[5]; e[6]=A[6]; e[7]=A[7];
    e[8]=B[7]; e[9]=B[6]; e[10]=B[5]; e[11]=B[4]; e[12]=B[3]; e[13]=B[2]; e[14]=B[1]; e[15]=B[0];
    bclean16f(e);
    merge_keep16f(e, 1);
    merge_keep16f(e, 2);
    merge_keep16f(e, 4);
    merge_keep16f(e, 8);
    merge_keep16f(e, 16);
    merge_keep16f(e, 32);
    if (lane == 0) ldsT = e[15];
  }
  __syncthreads();
  const float T = ldsT;

  // scan 2: collect from register cache (set semantics; ~16 hits/block; self has INF)
  #pragma unroll
  for (int t = 0; t < 32; ++t){
    if (dcache[t] <= T){
      int p = atomicAdd(&cnt, 1);
      if (p < 16) list[p] = mbase + t*64;
    }
  }
  __syncthreads();

  // exactness: pool subset => T >= T_true => cnt >= 16 always.
  // cnt == 16  <=>  collected set == exact top-16 AND no boundary ties (in d').
  if (cnt == 16){
    if (tid < 16) knn[(size_t)point*16 + tid] = list[tid];
    return;
  }
  if (wid != 0) return;

  // slow path (rare): known-correct 16-deep sorted insert + extraction, wave 0 only
  const float px = self.x, py = self.y, pz = self.z;
  const float* pb = pts + (size_t)b*NN*3;
  float d[16]; int id[16];
  #pragma unroll
  for (int j=0;j<16;++j){ d[j]=INFINITY; id[j]=0x7fffffff; }
  for (int m = lane; m < NN; m += 64){
    if (m == n) continue;
    float dx = pb[(size_t)m*3+0] - px;
    float dy = pb[(size_t)m*3+1] - py;
    float dz = pb[(size_t)m*3+2] - pz;
    float dist = dx*dx + dy*dy + dz*dz;
    if (dist < d[15] || (dist == d[15] && m < id[15])){
      float cd = dist; int ci = m;
      #pragma unroll
      for (int j=0;j<16;++j){
        bool sw = (cd < d[j]) || (cd == d[j] && ci < id[j]);
        float td = sw ? d[j] : cd; int ti = sw ? id[j] : ci;
        d[j]  = sw ? cd : d[j];
        id[j] = sw ? ci : id[j];
        cd = td; ci = ti;
      }
    }
  }
  for (int r=0; r<16; ++r){
    float bd = d[0]; int bi = id[0];
    for (int off=32; off>=1; off>>=1){
      float od = __shfl_xor(bd, off);
      int   oi = __shfl_xor(bi, off);
      bool take = (od < bd) || (od == bd && oi < bi);
      bd = take ? od : bd; bi = take ? oi : bi;
    }
    if (d[0] == bd && id[0] == bi){
      knn[(size_t)point*16 + r] = bi;
      #pragma unroll
      for (int j=0;j<15;++j){ d[j]=d[j+1]; id[j]=id[j+1]; }
      d[15]=INFINITY; id[15]=0x7fffffff;
    }
  }
}

// ------------- neighbor MLP + pool + ftr_1 (thread = point*16+k) -------------
__global__ __launch_bounds__(256) void nbr_kernel(
    const float* __restrict__ pts, const int* __restrict__ knn,
    const float* __restrict__ w1, const float* __restrict__ b1,
    const float* __restrict__ w2, const float* __restrict__ b2,
    const float* __restrict__ wp, const float* __restrict__ bp,
    const float* __restrict__ w3, const float* __restrict__ b3,
    float* __restrict__ ftr1)
{
  __shared__ float sw1[7*16], sb1[16], sw2[16*32], sb2[32], swp[3*32], sbp[32], sw3[64*32], sb3[32];
  for (int t = threadIdx.x; t < 7*16;  t += 256) sw1[t] = w1[t];
  for (int t = threadIdx.x; t < 16;    t += 256) sb1[t] = b1[t];
  for (int t = threadIdx.x; t < 16*32; t += 256) sw2[t] = w2[t];
  for (int t = threadIdx.x; t < 32;    t += 256) sb2[t] = b2[t];
  for (int t = threadIdx.x; t < 3*32;  t += 256) swp[t] = wp[t];
  for (int t = threadIdx.x; t < 32;    t += 256) sbp[t] = bp[t];
  for (int t = threadIdx.x; t < 64*32; t += 256) sw3[t] = w3[t];
  for (int t = threadIdx.x; t < 32;    t += 256) sb3[t] = b3[t];
  __syncthreads();
  int gt = blockIdx.x*256 + threadIdx.x;
  int point = gt >> 4;
  int k = gt & 15;
  int b = point >> 13;
  float ax = pts[(size_t)point*3+0];
  float ay = pts[(size_t)point*3+1];
  float az = pts[(size_t)point*3+2];
  int idx = knn[(size_t)point*16 + k] & (NN-1);
  size_t nb = ((size_t)b*NN + idx)*3;
  float rx = pts[nb+0] - ax;
  float ry = pts[nb+1] - ay;
  float rz = pts[nb+2] - az;
  float dd = sqrtf(rx*rx + ry*ry + rz*rz + 1e-8f);
  float in7[7] = {ax, ay, az, rx, ry, rz, dd};
  float h16[16];
  #pragma unroll
  for (int j=0;j<16;++j){
    float a = sb1[j];
    #pragma unroll
    for (int c=0;c<7;++c) a += in7[c]*sw1[c*16+j];
    h16[j] = fmaxf(a, 0.f);
  }
  float h32[32];
  #pragma unroll
  for (int j=0;j<32;++j){
    float a = sb2[j];
    #pragma unroll
    for (int c=0;c<16;++c) a += h16[c]*sw2[c*32+j];
    h32[j] = fmaxf(a, 0.f);
  }
  #pragma unroll
  for (int j=0;j<32;++j){
    h32[j] = fmaxf(h32[j], __shfl_xor(h32[j], 8));
    h32[j] = fmaxf(h32[j], __shfl_xor(h32[j], 4));
    h32[j] = fmaxf(h32[j], __shfl_xor(h32[j], 2));
    h32[j] = fmaxf(h32[j], __shfl_xor(h32[j], 1));
  }
  if (k == 0){
    float lift[32];
    #pragma unroll
    for (int j=0;j<32;++j){
      float a = sbp[j] + ax*swp[0*32+j] + ay*swp[1*32+j] + az*swp[2*32+j];
      lift[j] = fmaxf(a, 0.f);
    }
    #pragma unroll
    for (int j=0;j<32;++j){
      float a = sb3[j];
      #pragma unroll
      for (int c=0;c<32;++c) a += lift[c]*sw3[c*32+j];
      #pragma unroll
      for (int c=0;c<32;++c) a += h32[c]*sw3[(32+c)*32+j];
      ftr1[(size_t)point*32 + j] = fmaxf(a, 0.f);
    }
  }
}

// ------------- column max over N per batch -------------
__global__ __launch_bounds__(256) void colmax_kernel(const float* __restrict__ X, float* __restrict__ out, int J){
  int b  = blockIdx.y;
  int n0 = blockIdx.x * 256;
  int f  = threadIdx.x % J;
  int r0 = threadIdx.x / J;
  int step = 256 / J;
  float vm = 0.f;
  for (int n = n0 + r0; n < n0 + 256; n += step)
    vm = fmaxf(vm, X[((size_t)b*NN + n)*J + f]);
  atomicMax((int*)&out[b*J + f], __float_as_int(vm));
}

// ------- weight pack: W[K,J] f32 -> bf16 MFMA B-fragment order -------
__global__ __launch_bounds__(64) void packw_kernel(const float* __restrict__ W, s16* __restrict__ out, int J){
  int ntb = J >> 4;
  int kt = blockIdx.x / ntb, nt = blockIdx.x % ntb;
  int lane = threadIdx.x;
  int k0 = kt*32 + ((lane>>4)<<3);
  int n  = nt*16 + (lane & 15);
  s16 v[8];
  #pragma unroll
  for (int i=0;i<8;++i) v[i] = (s16)f2bf(W[(size_t)(k0+i)*J + n]);
  *(short8v*)(out + (((size_t)blockIdx.x)*64 + lane)*8) = *(short8v*)v;
}

// ------- online-softmax pairwise merge -------
__device__ __forceinline__ void omerge(float& m, float& s, float& a, float& f,
                                       float m2, float s2, float a2, float f2){
  float mn = fmaxf(m, m2);
  float e1 = __expf(m - mn), e2 = __expf(m2 - mn);
  s = s*e1 + s2*e2;
  a = a*e1 + a2*e2;
  m = mn;
  f = fmaxf(f, f2);
}

// ---- MFMA residual SMLP: Y = relu( relu(X@wa+ba)@wb + bb + X@ws + bs ) ----
template<int KIN, int JM>
__global__ __launch_bounds__(512) void resblock_mfma(
    const float* __restrict__ s0, int w0,
    const float* __restrict__ s1, int bc1,
    const s16* __restrict__ pwa, const float* __restrict__ ba,
    const s16* __restrict__ pwb, const float* __restrict__ bb,
    const s16* __restrict__ pws, const float* __restrict__ bs,
    float* __restrict__ Y)
{
  constexpr int XP  = KIN + 8;
  constexpr int AP  = JM + 8;
  constexpr int NTB = JM/16;
  constexpr int NTW = NTB/2;
  constexpr int KT1 = KIN/32;
  constexpr int KT2 = JM/32;
  __shared__ s16 xs[64*XP];
  __shared__ s16 as_[64*AP];
  const int tid  = threadIdx.x;
  const int lane = tid & 63;
  const int w    = tid >> 6;
  const int mt   = w >> 1;
  const int half = w & 1;
  const int l15  = lane & 15;
  const int lk   = lane >> 4;
  const int n0   = blockIdx.x * 64;

  for (int t = tid; t < 64*KIN; t += 512){
    int r = t / KIN, c = t - r*KIN;
    int row = n0 + r;
    float v = (c < w0) ? s0[(size_t)row*w0 + c]
                       : s1[(size_t)(bc1 ? (row>>13) : row)*(KIN-w0) + (c-w0)];
    xs[r*XP + c] = (s16)f2bf(v);
  }
  __syncthreads();

  {
    const s16* arow = xs + (mt*16 + l15)*XP + lk*8;
    const int rb = mt*16 + lk*4;
    #pragma unroll
    for (int ntg = 0; ntg < NTW; ++ntg){
      const int ntA = half*NTW + ntg;
      f32x4 acc = {0.f,0.f,0.f,0.f};
      #pragma unroll
      for (int kt = 0; kt < KT1; ++kt){
        short8v a = *(const short8v*)(arow + kt*32);
        short8v bfr = *(const short8v*)(pwa + (((size_t)kt*NTB + ntA)*64 + lane)*8);
        acc = __builtin_amdgcn_mfma_f32_16x16x32_bf16(a, bfr, acc, 0, 0, 0);
      }
      const int col = ntA*16 + l15;
      const float bv = ba[col];
      #pragma unroll
      for (int r=0;r<4;++r)
        as_[(rb+r)*AP + col] = (s16)f2bf(fmaxf(acc[r] + bv, 0.f));
    }
  }
  __syncthreads();

  {
    const s16* arowA = as_ + (mt*16 + l15)*AP + lk*8;
    const s16* arowX = xs  + (mt*16 + l15)*XP + lk*8;
    const int rb = mt*16 + lk*4;
    #pragma unroll
    for (int ntg = 0; ntg < NTW; ++ntg){
      const int ntA = half*NTW + ntg;
      f32x4 acc = {0.f,0.f,0.f,0.f};
      #pragma unroll
      for (int kt = 0; kt < KT2; ++kt){
        short8v a = *(const short8v*)(arowA + kt*32);
        short8v bfr = *(const short8v*)(pwb + (((size_t)kt*NTB + ntA)*64 + lane)*8);
        acc = __builtin_amdgcn_mfma_f32_16x16x32_bf16(a, bfr, acc, 0, 0, 0);
      }
      #pragma unroll
      for (int kt = 0; kt < KT1; ++kt){
        short8v a = *(const short8v*)(arowX + kt*32);
        short8v bfr = *(const short8v*)(pws + (((size_t)kt*NTB + ntA)*64 + lane)*8);
        acc = __builtin_amdgcn_mfma_f32_16x16x32_bf16(a, bfr, acc, 0, 0, 0);
      }
      const int col = ntA*16 + l15;
      const float bv = bb[col] + bs[col];
      #pragma unroll
      for (int r=0;r<4;++r)
        Y[(size_t)(n0 + rb + r)*JM + col] = fmaxf(acc[r] + bv, 0.f);
    }
  }
}

// ---- MFMA fused fuse-GEMM + att-GEMM + online softmax partials ----
__global__ __launch_bounds__(512) void fuseatt_mfma(
    const float* __restrict__ f1, const float* __restrict__ f2,
    const float* __restrict__ f3, const float* __restrict__ g3,
    const s16* __restrict__ pfw, const float* __restrict__ fb,
    const s16* __restrict__ paw, const float* __restrict__ ab,
    float4* __restrict__ part)
{
  __shared__ __align__(16) char arena[112640];
  s16*   f4s = (s16*)arena;                 // [64][520] bf16 ftr4 tile
  s16*   xs  = (s16*)(arena + 66560);       // [64][360] bf16 input tile
  float4* pb = (float4*)(arena + 66560);    // [4 mt][512 col] partials (aliases xs)
  const int chunk = blockIdx.x;
  const int tid  = threadIdx.x;
  const int lane = tid & 63;
  const int w    = tid >> 6;
  const int mt   = w >> 1;
  const int half = w & 1;
  const int l15  = lane & 15;
  const int lk   = lane >> 4;
  const int n0   = chunk*64;

  for (int t = tid; t < 64*352; t += 512){
    int r = t / 352, c = t - r*352;
    int row = n0 + r;
    float v;
    if (c < 32)       v = f1[(size_t)row*32 + c];
    else if (c < 96)  v = f2[(size_t)row*64 + (c-32)];
    else if (c < 224) v = f3[(size_t)row*128 + (c-96)];
    else              v = g3[(size_t)(row>>13)*128 + (c-224)];
    xs[r*360 + c] = (s16)f2bf(v);
  }
  __syncthreads();

  {
    const s16* arow = xs + (mt*16 + l15)*360 + lk*8;
    const int rb = mt*16 + lk*4;
    for (int ntg = 0; ntg < 16; ntg += 4){
      const int ntA = half*16 + ntg;
      f32x4 acc0={0,0,0,0}, acc1={0,0,0,0}, acc2={0,0,0,0}, acc3={0,0,0,0};
      for (int kt = 0; kt < 11; ++kt){
        short8v a = *(const short8v*)(arow + kt*32);
        const s16* bp = pfw + (((size_t)kt*32 + ntA)*64 + lane)*8;
        short8v b0 = *(const short8v*)(bp);
        short8v b1 = *(const short8v*)(bp + 512);
        short8v b2 = *(const short8v*)(bp + 1024);
        short8v b3 = *(const short8v*)(bp + 1536);
        acc0 = __builtin_amdgcn_mfma_f32_16x16x32_bf16(a, b0, acc0, 0, 0, 0);
        acc1 = __builtin_amdgcn_mfma_f32_16x16x32_bf16(a, b1, acc1, 0, 0, 0);
        acc2 = __builtin_amdgcn_mfma_f32_16x16x32_bf16(a, b2, acc2, 0, 0, 0);
        acc3 = __builtin_amdgcn_mfma_f32_16x16x32_bf16(a, b3, acc3, 0, 0, 0);
      }
      #define FUSE_EPI(ACC, J) { \
        int col = (ntA + (J))*16 + l15; float bv = fb[col]; \
        f4s[(rb+0)*520 + col] = (s16)f2bf(fmaxf(ACC[0] + bv, 0.f)); \
        f4s[(rb+1)*520 + col] = (s16)f2bf(fmaxf(ACC[1] + bv, 0.f)); \
        f4s[(rb+2)*520 + col] = (s16)f2bf(fmaxf(ACC[2] + bv, 0.f)); \
        f4s[(rb+3)*520 + col] = (s16)f2bf(fmaxf(ACC[3] + bv, 0.f)); }
      FUSE_EPI(acc0, 0) FUSE_EPI(acc1, 1) FUSE_EPI(acc2, 2) FUSE_EPI(acc3, 3)
      #undef FUSE_EPI
    }
  }
  __syncthreads();

  {
    const s16* arow = f4s + (mt*16 + l15)*520 + lk*8;
    const int rb = mt*16 + lk*4;
    for (int ntg = 0; ntg < 16; ntg += 4){
      const int ntA = half*16 + ntg;
      f32x4 acc0={0,0,0,0}, acc1={0,0,0,0}, acc2={0,0,0,0}, acc3={0,0,0,0};
      for (int kt = 0; kt < 16; ++kt){
        short8v a = *(const short8v*)(arow + kt*32);
        const s16* bp = paw + (((size_t)kt*32 + ntA)*64 + lane)*8;
        short8v b0 = *(const short8v*)(bp);
        short8v b1 = *(const short8v*)(bp + 512);
        short8v b2 = *(const short8v*)(bp + 1024);
        short8v b3 = *(const short8v*)(bp + 1536);
        acc0 = __builtin_amdgcn_mfma_f32_16x16x32_bf16(a, b0, acc0, 0, 0, 0);
        acc1 = __builtin_amdgcn_mfma_f32_16x16x32_bf16(a, b1, acc1, 0, 0, 0);
        acc2 = __builtin_amdgcn_mfma_f32_16x16x32_bf16(a, b2, acc2, 0, 0, 0);
        acc3 = __builtin_amdgcn_mfma_f32_16x16x32_bf16(a, b3, acc3, 0, 0, 0);
      }
      #define ATT_EPI(ACC, J) { \
        int col = (ntA + (J))*16 + l15; float lb = ab[col]; \
        float m_ = -INFINITY, s_ = 0.f, a_ = 0.f, fx_ = 0.f; \
        _Pragma("unroll") \
        for (int r = 0; r < 4; ++r){ \
          float lv = ACC[r] + lb; \
          float x  = bf2f((unsigned short)f4s[(rb+r)*520 + col]); \
          float mn = fmaxf(m_, lv); \
          float e0 = __expf(m_ - mn), e1 = __expf(lv - mn); \
          s_ = s_*e0 + e1; a_ = a_*e0 + x*e1; m_ = mn; fx_ = fmaxf(fx_, x); \
        } \
        { float om = __shfl_xor(m_,16), os = __shfl_xor(s_,16), oa = __shfl_xor(a_,16), of = __shfl_xor(fx_,16); \
          omerge(m_, s_, a_, fx_, om, os, oa, of); } \
        { float om = __shfl_xor(m_,32), os = __shfl_xor(s_,32), oa = __shfl_xor(a_,32), of = __shfl_xor(fx_,32); \
          omerge(m_, s_, a_, fx_, om, os, oa, of); } \
        if (lk == 0) pb[mt*512 + col] = make_float4(m_, s_, a_, fx_); }
      ATT_EPI(acc0, 0) ATT_EPI(acc1, 1) ATT_EPI(acc2, 2) ATT_EPI(acc3, 3)
      #undef ATT_EPI
    }
  }
  __syncthreads();

  {
    float4 p0 = pb[tid], p1 = pb[512 + tid], p2 = pb[1024 + tid], p3 = pb[1536 + tid];
    float m_ = p0.x, s_ = p0.y, a_ = p0.z, f_ = p0.w;
    omerge(m_, s_, a_, f_, p1.x, p1.y, p1.z, p1.w);
    omerge(m_, s_, a_, f_, p2.x, p2.y, p2.z, p2.w);
    omerge(m_, s_, a_, f_, p3.x, p3.y, p3.z, p3.w);
    part[(size_t)chunk*512 + tid] = make_float4(m_, s_, a_, f_);
  }
}

// ---- two-stage attention merge ----
__global__ __launch_bounds__(512) void attmerge1_kernel(const float4* __restrict__ part, float4* __restrict__ part2){
  int g = blockIdx.x;
  int b = blockIdx.y;
  int f = threadIdx.x;
  float m=-INFINITY, s=0.f, a=0.f, fx=0.f;
  for (int c = g*8; c < g*8+8; ++c){
    float4 p = part[((size_t)(b*128 + c))*512 + f];
    omerge(m, s, a, fx, p.x, p.y, p.z, p.w);
  }
  part2[((size_t)(b*16 + g))*512 + f] = make_float4(m, s, a, fx);
}

__global__ __launch_bounds__(256) void attmerge2_kernel(const float4* __restrict__ part2, float* __restrict__ feat){
  int t = blockIdx.x*256 + threadIdx.x;
  if (t >= BB*512) return;
  int b = t >> 9, f = t & 511;
  float m=-INFINITY, s=0.f, a=0.f, fx=0.f;
  for (int c=0;c<16;++c){
    float4 p = part2[((size_t)(b*16 + c))*512 + f];
    omerge(m, s, a, fx, p.x, p.y, p.z, p.w);
  }
  feat[(size_t)b*1024 + f] = fx;
  feat[(size_t)b*1024 + 512 + f] = a / s;
}

// ------------- head MLP v2: split-K with atomics -------------
__global__ __launch_bounds__(256) void headinit_kernel(const float* __restrict__ bias, float* __restrict__ Y, int J){
  int i = blockIdx.x*256 + threadIdx.x;
  if (i < 2*J) Y[i] = bias[i >= J ? i - J : i];
}
__global__ __launch_bounds__(256) void headpart_kernel(
    const float* __restrict__ X, const float* __restrict__ W, float* __restrict__ Y,
    int K, int J, int relu_in)
{
  const int j  = blockIdx.x*64 + (threadIdx.x & 63);
  const int k0 = blockIdx.y*128 + (threadIdx.x >> 6)*32;
  float acc0 = 0.f, acc1 = 0.f;
  #pragma unroll 8
  for (int k = 0; k < 32; ++k){
    float x0 = X[k0+k], x1 = X[K + k0+k];
    if (relu_in){ x0 = fmaxf(x0, 0.f); x1 = fmaxf(x1, 0.f); }
    float w = W[(size_t)(k0+k)*J + j];
    acc0 += x0*w; acc1 += x1*w;
  }
  atomicAdd(&Y[j], acc0);
  atomicAdd(&Y[J+j], acc1);
}

extern "C" void kernel_launch(void* const* d_in, const int* in_sizes, int n_in,
                              void* d_out, int out_size, void* d_ws, size_t ws_size,
                              hipStream_t stream)
{
  const float* pts    = (const float*)d_in[0];
  const float* na1w1  = (const float*)d_in[1];
  const float* na1b1  = (const float*)d_in[2];
  const float* na1w2  = (const float*)d_in[3];
  const float* na1b2  = (const float*)d_in[4];
  const float* na2w   = (const float*)d_in[5];
  const float* na2b   = (const float*)d_in[6];
  const float* na3w   = (const float*)d_in[7];
  const float* na3b   = (const float*)d_in[8];
  const float* r1aw   = (const float*)d_in[9];
  const float* r1ab   = (const float*)d_in[10];
  const float* r1bw   = (const float*)d_in[11];
  const float* r1bb   = (const float*)d_in[12];
  const float* r1sw   = (const float*)d_in[13];
  const float* r1sb   = (const float*)d_in[14];
  const float* r2aw   = (const float*)d_in[15];
  const float* r2ab   = (const float*)d_in[16];
  const float* r2bw   = (const float*)d_in[17];
  const float* r2bb   = (const float*)d_in[18];
  const float* r2sw   = (const float*)d_in[19];
  const float* r2sb   = (const float*)d_in[20];
  const float* fusew  = (const float*)d_in[21];
  const float* fuseb  = (const float*)d_in[22];
  const float* attw   = (const float*)d_in[23];
  const float* attb   = (const float*)d_in[24];
  const float* fc1w   = (const float*)d_in[25];
  const float* fc1b   = (const float*)d_in[26];
  const float* fc2w   = (const float*)d_in[27];
  const float* fc2b   = (const float*)d_in[28];
  const float* fc3w   = (const float*)d_in[29];
  const float* fc3b   = (const float*)d_in[30];

  if (n_in < 31) return;
  if (in_sizes[0] != NPTS*3) return;
  if (in_sizes[21] != 352*512) return;
  if (in_sizes[29] != 1024*1024) return;

  // Workspace layout (float offsets).
  const size_t o_ftr1 = 0;
  const size_t o_ftr2 = 524288;
  const size_t o_ftr3 = 1572864;
  const size_t o_knn  = 1572864;
  const size_t o_part = 3670016;
  const size_t o_g2   = 4194304;
  const size_t o_g3   = 4194432;
  const size_t o_feat = 4194688;
  const size_t o_h1   = 4196736;
  const size_t o_h2   = 4197760;
  const size_t o_pfw  = 4199808;
  const size_t o_paw  = o_pfw + 90112;
  const size_t mfma_bytes = 4420992ull * 4ull;
  if (ws_size < mfma_bytes) return;

  float* ws = (float*)d_ws;
  float*  ftr1  = ws + o_ftr1;
  float4* pts4  = (float4*)(ws + o_ftr1);
  float4* part2 = (float4*)(ws + o_ftr1);
  float*  ftr2 = ws + o_ftr2;
  float*  ftr3 = ws + o_ftr3;
  int*    knn  = (int*)(ws + o_knn);
  float4* part = (float4*)(ws + o_part);
  float*  g2   = ws + o_g2;
  float*  g3   = ws + o_g3;
  float*  feat = ws + o_feat;
  float*  h1   = ws + o_h1;
  float*  h2   = ws + o_h2;
  s16*    pfw  = (s16*)(ws + o_pfw);
  s16*    paw  = (s16*)(ws + o_paw);
  s16*    pr1a = (s16*)(ws + o_part);
  s16*    pr1b = pr1a + 2048;
  s16*    pr1s = pr1b + 4096;
  s16*    pr2a = pr1s + 2048;
  s16*    pr2b = pr2a + 16384;
  s16*    pr2s = pr2b + 16384;

  zero_kernel<<<2, 256, 0, stream>>>(g2, 384);
  packw_kernel<<<11*32, 64, 0, stream>>>(fusew, pfw, 512);
  packw_kernel<<<16*32, 64, 0, stream>>>(attw, paw, 512);
  packw_kernel<<<1*4,  64, 0, stream>>>(r1aw, pr1a, 64);
  packw_kernel<<<2*4,  64, 0, stream>>>(r1bw, pr1b, 64);
  packw_kernel<<<1*4,  64, 0, stream>>>(r1sw, pr1s, 64);
  packw_kernel<<<4*8,  64, 0, stream>>>(r2aw, pr2a, 128);
  packw_kernel<<<4*8,  64, 0, stream>>>(r2bw, pr2b, 128);
  packw_kernel<<<4*8,  64, 0, stream>>>(r2sw, pr2s, 128);
  pad4_kernel<<<NPTS/256, 256, 0, stream>>>(pts, pts4);
  knn_kernel<<<NPTS, 256, 0, stream>>>(pts, pts4, knn);
  nbr_kernel<<<NPTS*16/256, 256, 0, stream>>>(pts, knn, na1w1, na1b1, na1w2, na1b2,
                                              na2w, na2b, na3w, na3b, ftr1);
  resblock_mfma<32,64><<<NPTS/64, 512, 0, stream>>>(ftr1, 32, nullptr, 0,
                                                    pr1a, r1ab, pr1b, r1bb, pr1s, r1sb, ftr2);
  colmax_kernel<<<dim3(32,2), 256, 0, stream>>>(ftr2, g2, 64);
  resblock_mfma<128,128><<<NPTS/64, 512, 0, stream>>>(ftr2, 64, g2, 1,
                                                      pr2a, r2ab, pr2b, r2bb, pr2s, r2sb, ftr3);
  colmax_kernel<<<dim3(32,2), 256, 0, stream>>>(ftr3, g3, 128);
  fuseatt_mfma<<<NPTS/64, 512, 0, stream>>>(ftr1, ftr2, ftr3, g3,
                                            pfw, fuseb, paw, attb, part);
  attmerge1_kernel<<<dim3(16,2), 512, 0, stream>>>(part, part2);
  attmerge2_kernel<<<4, 256, 0, stream>>>(part2, feat);
  headinit_kernel<<<4, 256, 0, stream>>>(fc1b, h1, 512);
  headpart_kernel<<<dim3(8, 8),  256, 0, stream>>>(feat, fc1w, h1, 1024, 512, 0);
  headinit_kernel<<<8, 256, 0, stream>>>(fc2b, h2, 1024);
  headpart_kernel<<<dim3(16, 4), 256, 0, stream>>>(h1, fc2w, h2, 512, 1024, 1);
  headinit_kernel<<<8, 256, 0, stream>>>(fc3b, (float*)d_out, 1024);
  headpart_kernel<<<dim3(16, 8), 256, 0, stream>>>(h2, fc3w, (float*)d_out, 1024, 1024, 1);
}

// Round 18
// 288.814 us; speedup vs baseline: 1.1925x; 1.1925x over previous
//
#include <hip/hip_runtime.h>
#include <math.h>

#define BB 2
#define NN 8192
#define NPTS (BB*NN)

typedef unsigned long long u64;
typedef short s16;
typedef __attribute__((ext_vector_type(8))) short short8v;
typedef __attribute__((ext_vector_type(4))) float f32x4;

__device__ __forceinline__ unsigned short f2bf(float v){
  unsigned u = __float_as_uint(v);
  return (unsigned short)((u + 0x7FFFu + ((u >> 16) & 1u)) >> 16);
}
__device__ __forceinline__ float bf2f(unsigned short h){
  return __uint_as_float(((unsigned)h) << 16);
}

// ---------------- zero init (g2/g3 atomic-max targets) ----------------
__global__ __launch_bounds__(256) void zero_kernel(float* p, int n){
  int i = blockIdx.x*256 + threadIdx.x;
  if (i < n) p[i] = 0.f;
}

// ---------------- pts -> float4 pad (aliases dead ftr1 region) ----------------
__global__ __launch_bounds__(256) void pad4_kernel(const float* __restrict__ pts, float4* __restrict__ pts4){
  int i = blockIdx.x*256 + threadIdx.x;
  if (i < NPTS) pts4[i] = make_float4(pts[(size_t)i*3], pts[(size_t)i*3+1], pts[(size_t)i*3+2], 0.f);
}

// ---------------- KNN helpers: f32 branchless bitonic primitives (validated) ----------------
__device__ __forceinline__ void fce(float& a, float& b){
  float lo = fminf(a, b), hi = fmaxf(a, b);
  a = lo; b = hi;
}

__device__ __forceinline__ void bclean16f(float e[16]){
  #pragma unroll
  for (int i=0;i<8;++i) fce(e[i], e[i+8]);
  #pragma unroll
  for (int g=0; g<2; ++g){
    #pragma unroll
    for (int i=0;i<4;++i) fce(e[g*8+i], e[g*8+i+4]);
  }
  #pragma unroll
  for (int g=0; g<4; ++g){
    #pragma unroll
    for (int i=0;i<2;++i) fce(e[g*4+i], e[g*4+i+2]);
  }
  #pragma unroll
  for (int g=0; g<8; ++g) fce(e[g*2], e[g*2+1]);
}

__device__ __forceinline__ void clean8f(float A[8]){
  fce(A[0],A[4]); fce(A[1],A[5]); fce(A[2],A[6]); fce(A[3],A[7]);
  fce(A[0],A[2]); fce(A[1],A[3]); fce(A[4],A[6]); fce(A[5],A[7]);
  fce(A[0],A[1]); fce(A[2],A[3]); fce(A[4],A[5]); fce(A[6],A[7]);
}

__device__ __forceinline__ void merge_keep16f(float e[16], int maskXor){
  float p[16];
  #pragma unroll
  for (int i=0;i<16;++i) p[i] = __shfl_xor(e[i], maskXor);
  #pragma unroll
  for (int i=0;i<16;++i){ float o = p[15-i]; e[i] = fminf(e[i], o); }
  bclean16f(e);
}

// ---- KNN v7: dist-only scan (register-cached) + f32 threshold + count-verified collection ----
__global__ __launch_bounds__(256) void knn_kernel(const float* __restrict__ pts,
                                                  const float4* __restrict__ pts4,
                                                  int* __restrict__ knn){
  __shared__ float poold[1024];           // [slot 0..15][col 0..63]
  __shared__ float ldsT;
  __shared__ int   cnt;
  __shared__ int   list[16];
  const int tid  = threadIdx.x;
  const int wid  = tid >> 6;
  const int lane = tid & 63;
  const int point = blockIdx.x;
  const int b = point >> 13;
  const int n = point & (NN-1);
  const float4* pb4 = pts4 + (size_t)b*NN;
  const float4 self = pb4[n];
  const float px = self.x, py = self.y, pz = self.z;

  // scan 1: per-lane top-4 DISTANCES (med3 sorted-insert), distances register-cached
  float dcache[32];
  float d0=INFINITY, d1=INFINITY, d2=INFINITY, d3=INFINITY;
  const int mbase = wid*2048 + lane;
  #pragma unroll
  for (int t = 0; t < 32; ++t){
    int m = mbase + t*64;
    float4 q = pb4[m];
    float dx = q.x - px, dy = q.y - py, dz = q.z - pz;
    float dist = dx*dx + dy*dy + dz*dz;
    dist = (m == n) ? INFINITY : dist;    // exclude self (stays excluded in scan 2)
    dcache[t] = dist;
    float n3 = __builtin_amdgcn_fmed3f(dist, d2, d3);
    float n2 = __builtin_amdgcn_fmed3f(dist, d1, d2);
    float n1 = __builtin_amdgcn_fmed3f(dist, d0, d1);
    float n0 = fminf(dist, d0);
    d3=n3; d2=n2; d1=n1; d0=n0;
  }

  // pool: thread t=(col=t>>2, j=t&3) writes sorted-4 run to slots j*4..j*4+3, column col
  {
    const int j = tid & 3, col = tid >> 2;
    poold[(j*4+0)*64 + col] = d0;
    poold[(j*4+1)*64 + col] = d1;
    poold[(j*4+2)*64 + col] = d2;
    poold[(j*4+3)*64 + col] = d3;
  }
  if (tid == 0) cnt = 0;
  __syncthreads();

  // wave 0: f32 selection network (validated) -> T = pooled 16th-smallest distance
  if (wid == 0){
    float r[16];
    #pragma unroll
    for (int s=0;s<16;++s) r[s] = poold[s*64 + lane];
    float A[8] = {r[0],r[1],r[2],r[3],r[7],r[6],r[5],r[4]};
    clean8f(A);
    float B[8] = {r[8],r[9],r[10],r[11],r[15],r[14],r[13],r[12]};
    clean8f(B);
    float e[16];
    e[0]=A[0]; e[1]=A[1]; e[2]=A[2]; e[3]=A[3]; e[4]=A[4]; e[5]=A[5]; e[6]=A[6]; e[7]=A[7];
    e[8]=B[7]; e[9]=B[6]; e[10]=B[5]; e[11]=B[4]; e[12]=B[3]; e[13]=B[2]; e[14]=B[1]; e[15]=B[0];
    bclean16f(e);
    merge_keep16f(e, 1);
    merge_keep16f(e, 2);
    merge_keep16f(e, 4);
    merge_keep16f(e, 8);
    merge_keep16f(e, 16);
    merge_keep16f(e, 32);
    if (lane == 0) ldsT = e[15];
  }
  __syncthreads();
  const float T = ldsT;

  // scan 2: collect from register cache (set semantics; ~16 hits/block; self has INF)
  #pragma unroll
  for (int t = 0; t < 32; ++t){
    if (dcache[t] <= T){
      int p = atomicAdd(&cnt, 1);
      if (p < 16) list[p] = mbase + t*64;
    }
  }
  __syncthreads();

  // exactness: pool subset => T >= T_true => cnt >= 16 always.
  // cnt == 16  <=>  collected set == exact top-16 AND no boundary distance ties.
  if (cnt == 16){
    if (tid < 16) knn[(size_t)point*16 + tid] = list[tid];
    return;
  }
  if (wid != 0) return;

  // slow path (rare): known-correct 16-deep sorted insert + extraction, wave 0 only
  const float* pb = pts + (size_t)b*NN*3;
  float d[16]; int id[16];
  #pragma unroll
  for (int j=0;j<16;++j){ d[j]=INFINITY; id[j]=0x7fffffff; }
  for (int m = lane; m < NN; m += 64){
    if (m == n) continue;
    float dx = pb[(size_t)m*3+0] - px;
    float dy = pb[(size_t)m*3+1] - py;
    float dz = pb[(size_t)m*3+2] - pz;
    float dist = dx*dx + dy*dy + dz*dz;
    if (dist < d[15] || (dist == d[15] && m < id[15])){
      float cd = dist; int ci = m;
      #pragma unroll
      for (int j=0;j<16;++j){
        bool sw = (cd < d[j]) || (cd == d[j] && ci < id[j]);
        float td = sw ? d[j] : cd; int ti = sw ? id[j] : ci;
        d[j]  = sw ? cd : d[j];
        id[j] = sw ? ci : id[j];
        cd = td; ci = ti;
      }
    }
  }
  for (int r=0; r<16; ++r){
    float bd = d[0]; int bi = id[0];
    for (int off=32; off>=1; off>>=1){
      float od = __shfl_xor(bd, off);
      int   oi = __shfl_xor(bi, off);
      bool take = (od < bd) || (od == bd && oi < bi);
      bd = take ? od : bd; bi = take ? oi : bi;
    }
    if (d[0] == bd && id[0] == bi){
      knn[(size_t)point*16 + r] = bi;
      #pragma unroll
      for (int j=0;j<15;++j){ d[j]=d[j+1]; id[j]=id[j+1]; }
      d[15]=INFINITY; id[15]=0x7fffffff;
    }
  }
}

// ------------- neighbor MLP + pool + ftr_1 (thread = point*16+k) -------------
__global__ __launch_bounds__(256) void nbr_kernel(
    const float* __restrict__ pts, const int* __restrict__ knn,
    const float* __restrict__ w1, const float* __restrict__ b1,
    const float* __restrict__ w2, const float* __restrict__ b2,
    const float* __restrict__ wp, const float* __restrict__ bp,
    const float* __restrict__ w3, const float* __restrict__ b3,
    float* __restrict__ ftr1)
{
  __shared__ float sw1[7*16], sb1[16], sw2[16*32], sb2[32], swp[3*32], sbp[32], sw3[64*32], sb3[32];
  for (int t = threadIdx.x; t < 7*16;  t += 256) sw1[t] = w1[t];
  for (int t = threadIdx.x; t < 16;    t += 256) sb1[t] = b1[t];
  for (int t = threadIdx.x; t < 16*32; t += 256) sw2[t] = w2[t];
  for (int t = threadIdx.x; t < 32;    t += 256) sb2[t] = b2[t];
  for (int t = threadIdx.x; t < 3*32;  t += 256) swp[t] = wp[t];
  for (int t = threadIdx.x; t < 32;    t += 256) sbp[t] = bp[t];
  for (int t = threadIdx.x; t < 64*32; t += 256) sw3[t] = w3[t];
  for (int t = threadIdx.x; t < 32;    t += 256) sb3[t] = b3[t];
  __syncthreads();
  int gt = blockIdx.x*256 + threadIdx.x;
  int point = gt >> 4;
  int k = gt & 15;
  int b = point >> 13;
  float ax = pts[(size_t)point*3+0];
  float ay = pts[(size_t)point*3+1];
  float az = pts[(size_t)point*3+2];
  int idx = knn[(size_t)point*16 + k] & (NN-1);
  size_t nb = ((size_t)b*NN + idx)*3;
  float rx = pts[nb+0] - ax;
  float ry = pts[nb+1] - ay;
  float rz = pts[nb+2] - az;
  float dd = sqrtf(rx*rx + ry*ry + rz*rz + 1e-8f);
  float in7[7] = {ax, ay, az, rx, ry, rz, dd};
  float h16[16];
  #pragma unroll
  for (int j=0;j<16;++j){
    float a = sb1[j];
    #pragma unroll
    for (int c=0;c<7;++c) a += in7[c]*sw1[c*16+j];
    h16[j] = fmaxf(a, 0.f);
  }
  float h32[32];
  #pragma unroll
  for (int j=0;j<32;++j){
    float a = sb2[j];
    #pragma unroll
    for (int c=0;c<16;++c) a += h16[c]*sw2[c*32+j];
    h32[j] = fmaxf(a, 0.f);
  }
  #pragma unroll
  for (int j=0;j<32;++j){
    h32[j] = fmaxf(h32[j], __shfl_xor(h32[j], 8));
    h32[j] = fmaxf(h32[j], __shfl_xor(h32[j], 4));
    h32[j] = fmaxf(h32[j], __shfl_xor(h32[j], 2));
    h32[j] = fmaxf(h32[j], __shfl_xor(h32[j], 1));
  }
  if (k == 0){
    float lift[32];
    #pragma unroll
    for (int j=0;j<32;++j){
      float a = sbp[j] + ax*swp[0*32+j] + ay*swp[1*32+j] + az*swp[2*32+j];
      lift[j] = fmaxf(a, 0.f);
    }
    #pragma unroll
    for (int j=0;j<32;++j){
      float a = sb3[j];
      #pragma unroll
      for (int c=0;c<32;++c) a += lift[c]*sw3[c*32+j];
      #pragma unroll
      for (int c=0;c<32;++c) a += h32[c]*sw3[(32+c)*32+j];
      ftr1[(size_t)point*32 + j] = fmaxf(a, 0.f);
    }
  }
}

// ------------- column max over N per batch -------------
__global__ __launch_bounds__(256) void colmax_kernel(const float* __restrict__ X, float* __restrict__ out, int J){
  int b  = blockIdx.y;
  int n0 = blockIdx.x * 256;
  int f  = threadIdx.x % J;
  int r0 = threadIdx.x / J;
  int step = 256 / J;
  float vm = 0.f;
  for (int n = n0 + r0; n < n0 + 256; n += step)
    vm = fmaxf(vm, X[((size_t)b*NN + n)*J + f]);
  atomicMax((int*)&out[b*J + f], __float_as_int(vm));
}

// ------- weight pack: W[K,J] f32 -> bf16 MFMA B-fragment order -------
__global__ __launch_bounds__(64) void packw_kernel(const float* __restrict__ W, s16* __restrict__ out, int J){
  int ntb = J >> 4;
  int kt = blockIdx.x / ntb, nt = blockIdx.x % ntb;
  int lane = threadIdx.x;
  int k0 = kt*32 + ((lane>>4)<<3);
  int n  = nt*16 + (lane & 15);
  s16 v[8];
  #pragma unroll
  for (int i=0;i<8;++i) v[i] = (s16)f2bf(W[(size_t)(k0+i)*J + n]);
  *(short8v*)(out + (((size_t)blockIdx.x)*64 + lane)*8) = *(short8v*)v;
}

// ------- online-softmax pairwise merge -------
__device__ __forceinline__ void omerge(float& m, float& s, float& a, float& f,
                                       float m2, float s2, float a2, float f2){
  float mn = fmaxf(m, m2);
  float e1 = __expf(m - mn), e2 = __expf(m2 - mn);
  s = s*e1 + s2*e2;
  a = a*e1 + a2*e2;
  m = mn;
  f = fmaxf(f, f2);
}

// ---- MFMA residual SMLP: Y = relu( relu(X@wa+ba)@wb + bb + X@ws + bs ) ----
template<int KIN, int JM>
__global__ __launch_bounds__(512) void resblock_mfma(
    const float* __restrict__ s0, int w0,
    const float* __restrict__ s1, int bc1,
    const s16* __restrict__ pwa, const float* __restrict__ ba,
    const s16* __restrict__ pwb, const float* __restrict__ bb,
    const s16* __restrict__ pws, const float* __restrict__ bs,
    float* __restrict__ Y)
{
  constexpr int XP  = KIN + 8;
  constexpr int AP  = JM + 8;
  constexpr int NTB = JM/16;
  constexpr int NTW = NTB/2;
  constexpr int KT1 = KIN/32;
  constexpr int KT2 = JM/32;
  __shared__ s16 xs[64*XP];
  __shared__ s16 as_[64*AP];
  const int tid  = threadIdx.x;
  const int lane = tid & 63;
  const int w    = tid >> 6;
  const int mt   = w >> 1;
  const int half = w & 1;
  const int l15  = lane & 15;
  const int lk   = lane >> 4;
  const int n0   = blockIdx.x * 64;

  for (int t = tid; t < 64*KIN; t += 512){
    int r = t / KIN, c = t - r*KIN;
    int row = n0 + r;
    float v = (c < w0) ? s0[(size_t)row*w0 + c]
                       : s1[(size_t)(bc1 ? (row>>13) : row)*(KIN-w0) + (c-w0)];
    xs[r*XP + c] = (s16)f2bf(v);
  }
  __syncthreads();

  {
    const s16* arow = xs + (mt*16 + l15)*XP + lk*8;
    const int rb = mt*16 + lk*4;
    #pragma unroll
    for (int ntg = 0; ntg < NTW; ++ntg){
      const int ntA = half*NTW + ntg;
      f32x4 acc = {0.f,0.f,0.f,0.f};
      #pragma unroll
      for (int kt = 0; kt < KT1; ++kt){
        short8v a = *(const short8v*)(arow + kt*32);
        short8v bfr = *(const short8v*)(pwa + (((size_t)kt*NTB + ntA)*64 + lane)*8);
        acc = __builtin_amdgcn_mfma_f32_16x16x32_bf16(a, bfr, acc, 0, 0, 0);
      }
      const int col = ntA*16 + l15;
      const float bv = ba[col];
      #pragma unroll
      for (int r=0;r<4;++r)
        as_[(rb+r)*AP + col] = (s16)f2bf(fmaxf(acc[r] + bv, 0.f));
    }
  }
  __syncthreads();

  {
    const s16* arowA = as_ + (mt*16 + l15)*AP + lk*8;
    const s16* arowX = xs  + (mt*16 + l15)*XP + lk*8;
    const int rb = mt*16 + lk*4;
    #pragma unroll
    for (int ntg = 0; ntg < NTW; ++ntg){
      const int ntA = half*NTW + ntg;
      f32x4 acc = {0.f,0.f,0.f,0.f};
      #pragma unroll
      for (int kt = 0; kt < KT2; ++kt){
        short8v a = *(const short8v*)(arowA + kt*32);
        short8v bfr = *(const short8v*)(pwb + (((size_t)kt*NTB + ntA)*64 + lane)*8);
        acc = __builtin_amdgcn_mfma_f32_16x16x32_bf16(a, bfr, acc, 0, 0, 0);
      }
      #pragma unroll
      for (int kt = 0; kt < KT1; ++kt){
        short8v a = *(const short8v*)(arowX + kt*32);
        short8v bfr = *(const short8v*)(pws + (((size_t)kt*NTB + ntA)*64 + lane)*8);
        acc = __builtin_amdgcn_mfma_f32_16x16x32_bf16(a, bfr, acc, 0, 0, 0);
      }
      const int col = ntA*16 + l15;
      const float bv = bb[col] + bs[col];
      #pragma unroll
      for (int r=0;r<4;++r)
        Y[(size_t)(n0 + rb + r)*JM + col] = fmaxf(acc[r] + bv, 0.f);
    }
  }
}

// ---- MFMA fused fuse-GEMM + att-GEMM + online softmax partials ----
__global__ __launch_bounds__(512) void fuseatt_mfma(
    const float* __restrict__ f1, const float* __restrict__ f2,
    const float* __restrict__ f3, const float* __restrict__ g3,
    const s16* __restrict__ pfw, const float* __restrict__ fb,
    const s16* __restrict__ paw, const float* __restrict__ ab,
    float4* __restrict__ part)
{
  __shared__ __align__(16) char arena[112640];
  s16*   f4s = (s16*)arena;                 // [64][520] bf16 ftr4 tile
  s16*   xs  = (s16*)(arena + 66560);       // [64][360] bf16 input tile
  float4* pb = (float4*)(arena + 66560);    // [4 mt][512 col] partials (aliases xs)
  const int chunk = blockIdx.x;
  const int tid  = threadIdx.x;
  const int lane = tid & 63;
  const int w    = tid >> 6;
  const int mt   = w >> 1;
  const int half = w & 1;
  const int l15  = lane & 15;
  const int lk   = lane >> 4;
  const int n0   = chunk*64;

  for (int t = tid; t < 64*352; t += 512){
    int r = t / 352, c = t - r*352;
    int row = n0 + r;
    float v;
    if (c < 32)       v = f1[(size_t)row*32 + c];
    else if (c < 96)  v = f2[(size_t)row*64 + (c-32)];
    else if (c < 224) v = f3[(size_t)row*128 + (c-96)];
    else              v = g3[(size_t)(row>>13)*128 + (c-224)];
    xs[r*360 + c] = (s16)f2bf(v);
  }
  __syncthreads();

  {
    const s16* arow = xs + (mt*16 + l15)*360 + lk*8;
    const int rb = mt*16 + lk*4;
    for (int ntg = 0; ntg < 16; ntg += 4){
      const int ntA = half*16 + ntg;
      f32x4 acc0={0,0,0,0}, acc1={0,0,0,0}, acc2={0,0,0,0}, acc3={0,0,0,0};
      for (int kt = 0; kt < 11; ++kt){
        short8v a = *(const short8v*)(arow + kt*32);
        const s16* bp = pfw + (((size_t)kt*32 + ntA)*64 + lane)*8;
        short8v b0 = *(const short8v*)(bp);
        short8v b1 = *(const short8v*)(bp + 512);
        short8v b2 = *(const short8v*)(bp + 1024);
        short8v b3 = *(const short8v*)(bp + 1536);
        acc0 = __builtin_amdgcn_mfma_f32_16x16x32_bf16(a, b0, acc0, 0, 0, 0);
        acc1 = __builtin_amdgcn_mfma_f32_16x16x32_bf16(a, b1, acc1, 0, 0, 0);
        acc2 = __builtin_amdgcn_mfma_f32_16x16x32_bf16(a, b2, acc2, 0, 0, 0);
        acc3 = __builtin_amdgcn_mfma_f32_16x16x32_bf16(a, b3, acc3, 0, 0, 0);
      }
      #define FUSE_EPI(ACC, J) { \
        int col = (ntA + (J))*16 + l15; float bv = fb[col]; \
        f4s[(rb+0)*520 + col] = (s16)f2bf(fmaxf(ACC[0] + bv, 0.f)); \
        f4s[(rb+1)*520 + col] = (s16)f2bf(fmaxf(ACC[1] + bv, 0.f)); \
        f4s[(rb+2)*520 + col] = (s16)f2bf(fmaxf(ACC[2] + bv, 0.f)); \
        f4s[(rb+3)*520 + col] = (s16)f2bf(fmaxf(ACC[3] + bv, 0.f)); }
      FUSE_EPI(acc0, 0) FUSE_EPI(acc1, 1) FUSE_EPI(acc2, 2) FUSE_EPI(acc3, 3)
      #undef FUSE_EPI
    }
  }
  __syncthreads();

  {
    const s16* arow = f4s + (mt*16 + l15)*520 + lk*8;
    const int rb = mt*16 + lk*4;
    for (int ntg = 0; ntg < 16; ntg += 4){
      const int ntA = half*16 + ntg;
      f32x4 acc0={0,0,0,0}, acc1={0,0,0,0}, acc2={0,0,0,0}, acc3={0,0,0,0};
      for (int kt = 0; kt < 16; ++kt){
        short8v a = *(const short8v*)(arow + kt*32);
        const s16* bp = paw + (((size_t)kt*32 + ntA)*64 + lane)*8;
        short8v b0 = *(const short8v*)(bp);
        short8v b1 = *(const short8v*)(bp + 512);
        short8v b2 = *(const short8v*)(bp + 1024);
        short8v b3 = *(const short8v*)(bp + 1536);
        acc0 = __builtin_amdgcn_mfma_f32_16x16x32_bf16(a, b0, acc0, 0, 0, 0);
        acc1 = __builtin_amdgcn_mfma_f32_16x16x32_bf16(a, b1, acc1, 0, 0, 0);
        acc2 = __builtin_amdgcn_mfma_f32_16x16x32_bf16(a, b2, acc2, 0, 0, 0);
        acc3 = __builtin_amdgcn_mfma_f32_16x16x32_bf16(a, b3, acc3, 0, 0, 0);
      }
      #define ATT_EPI(ACC, J) { \
        int col = (ntA + (J))*16 + l15; float lb = ab[col]; \
        float m_ = -INFINITY, s_ = 0.f, a_ = 0.f, fx_ = 0.f; \
        _Pragma("unroll") \
        for (int r = 0; r < 4; ++r){ \
          float lv = ACC[r] + lb; \
          float x  = bf2f((unsigned short)f4s[(rb+r)*520 + col]); \
          float mn = fmaxf(m_, lv); \
          float e0 = __expf(m_ - mn), e1 = __expf(lv - mn); \
          s_ = s_*e0 + e1; a_ = a_*e0 + x*e1; m_ = mn; fx_ = fmaxf(fx_, x); \
        } \
        { float om = __shfl_xor(m_,16), os = __shfl_xor(s_,16), oa = __shfl_xor(a_,16), of = __shfl_xor(fx_,16); \
          omerge(m_, s_, a_, fx_, om, os, oa, of); } \
        { float om = __shfl_xor(m_,32), os = __shfl_xor(s_,32), oa = __shfl_xor(a_,32), of = __shfl_xor(fx_,32); \
          omerge(m_, s_, a_, fx_, om, os, oa, of); } \
        if (lk == 0) pb[mt*512 + col] = make_float4(m_, s_, a_, fx_); }
      ATT_EPI(acc0, 0) ATT_EPI(acc1, 1) ATT_EPI(acc2, 2) ATT_EPI(acc3, 3)
      #undef ATT_EPI
    }
  }
  __syncthreads();

  {
    float4 p0 = pb[tid], p1 = pb[512 + tid], p2 = pb[1024 + tid], p3 = pb[1536 + tid];
    float m_ = p0.x, s_ = p0.y, a_ = p0.z, f_ = p0.w;
    omerge(m_, s_, a_, f_, p1.x, p1.y, p1.z, p1.w);
    omerge(m_, s_, a_, f_, p2.x, p2.y, p2.z, p2.w);
    omerge(m_, s_, a_, f_, p3.x, p3.y, p3.z, p3.w);
    part[(size_t)chunk*512 + tid] = make_float4(m_, s_, a_, f_);
  }
}

// ---- two-stage attention merge ----
__global__ __launch_bounds__(512) void attmerge1_kernel(const float4* __restrict__ part, float4* __restrict__ part2){
  int g = blockIdx.x;
  int b = blockIdx.y;
  int f = threadIdx.x;
  float m=-INFINITY, s=0.f, a=0.f, fx=0.f;
  for (int c = g*8; c < g*8+8; ++c){
    float4 p = part[((size_t)(b*128 + c))*512 + f];
    omerge(m, s, a, fx, p.x, p.y, p.z, p.w);
  }
  part2[((size_t)(b*16 + g))*512 + f] = make_float4(m, s, a, fx);
}

__global__ __launch_bounds__(256) void attmerge2_kernel(const float4* __restrict__ part2, float* __restrict__ feat){
  int t = blockIdx.x*256 + threadIdx.x;
  if (t >= BB*512) return;
  int b = t >> 9, f = t & 511;
  float m=-INFINITY, s=0.f, a=0.f, fx=0.f;
  for (int c=0;c<16;++c){
    float4 p = part2[((size_t)(b*16 + c))*512 + f];
    omerge(m, s, a, fx, p.x, p.y, p.z, p.w);
  }
  feat[(size_t)b*1024 + f] = fx;
  feat[(size_t)b*1024 + 512 + f] = a / s;
}

// ------------- head MLP v2: split-K with atomics -------------
__global__ __launch_bounds__(256) void headinit_kernel(const float* __restrict__ bias, float* __restrict__ Y, int J){
  int i = blockIdx.x*256 + threadIdx.x;
  if (i < 2*J) Y[i] = bias[i >= J ? i - J : i];
}
__global__ __launch_bounds__(256) void headpart_kernel(
    const float* __restrict__ X, const float* __restrict__ W, float* __restrict__ Y,
    int K, int J, int relu_in)
{
  const int j  = blockIdx.x*64 + (threadIdx.x & 63);
  const int k0 = blockIdx.y*128 + (threadIdx.x >> 6)*32;
  float acc0 = 0.f, acc1 = 0.f;
  #pragma unroll 8
  for (int k = 0; k < 32; ++k){
    float x0 = X[k0+k], x1 = X[K + k0+k];
    if (relu_in){ x0 = fmaxf(x0, 0.f); x1 = fmaxf(x1, 0.f); }
    float w = W[(size_t)(k0+k)*J + j];
    acc0 += x0*w; acc1 += x1*w;
  }
  atomicAdd(&Y[j], acc0);
  atomicAdd(&Y[J+j], acc1);
}

extern "C" void kernel_launch(void* const* d_in, const int* in_sizes, int n_in,
                              void* d_out, int out_size, void* d_ws, size_t ws_size,
                              hipStream_t stream)
{
  const float* pts    = (const float*)d_in[0];
  const float* na1w1  = (const float*)d_in[1];
  const float* na1b1  = (const float*)d_in[2];
  const float* na1w2  = (const float*)d_in[3];
  const float* na1b2  = (const float*)d_in[4];
  const float* na2w   = (const float*)d_in[5];
  const float* na2b   = (const float*)d_in[6];
  const float* na3w   = (const float*)d_in[7];
  const float* na3b   = (const float*)d_in[8];
  const float* r1aw   = (const float*)d_in[9];
  const float* r1ab   = (const float*)d_in[10];
  const float* r1bw   = (const float*)d_in[11];
  const float* r1bb   = (const float*)d_in[12];
  const float* r1sw   = (const float*)d_in[13];
  const float* r1sb   = (const float*)d_in[14];
  const float* r2aw   = (const float*)d_in[15];
  const float* r2ab   = (const float*)d_in[16];
  const float* r2bw   = (const float*)d_in[17];
  const float* r2bb   = (const float*)d_in[18];
  const float* r2sw   = (const float*)d_in[19];
  const float* r2sb   = (const float*)d_in[20];
  const float* fusew  = (const float*)d_in[21];
  const float* fuseb  = (const float*)d_in[22];
  const float* attw   = (const float*)d_in[23];
  const float* attb   = (const float*)d_in[24];
  const float* fc1w   = (const float*)d_in[25];
  const float* fc1b   = (const float*)d_in[26];
  const float* fc2w   = (const float*)d_in[27];
  const float* fc2b   = (const float*)d_in[28];
  const float* fc3w   = (const float*)d_in[29];
  const float* fc3b   = (const float*)d_in[30];

  if (n_in < 31) return;
  if (in_sizes[0] != NPTS*3) return;
  if (in_sizes[21] != 352*512) return;
  if (in_sizes[29] != 1024*1024) return;

  // Workspace layout (float offsets).
  const size_t o_ftr1 = 0;
  const size_t o_ftr2 = 524288;
  const size_t o_ftr3 = 1572864;
  const size_t o_knn  = 1572864;
  const size_t o_part = 3670016;
  const size_t o_g2   = 4194304;
  const size_t o_g3   = 4194432;
  const size_t o_feat = 4194688;
  const size_t o_h1   = 4196736;
  const size_t o_h2   = 4197760;
  const size_t o_pfw  = 4199808;
  const size_t o_paw  = o_pfw + 90112;
  const size_t mfma_bytes = 4420992ull * 4ull;
  if (ws_size < mfma_bytes) return;

  float* ws = (float*)d_ws;
  float*  ftr1  = ws + o_ftr1;
  float4* pts4  = (float4*)(ws + o_ftr1);
  float4* part2 = (float4*)(ws + o_ftr1);
  float*  ftr2 = ws + o_ftr2;
  float*  ftr3 = ws + o_ftr3;
  int*    knn  = (int*)(ws + o_knn);
  float4* part = (float4*)(ws + o_part);
  float*  g2   = ws + o_g2;
  float*  g3   = ws + o_g3;
  float*  feat = ws + o_feat;
  float*  h1   = ws + o_h1;
  float*  h2   = ws + o_h2;
  s16*    pfw  = (s16*)(ws + o_pfw);
  s16*    paw  = (s16*)(ws + o_paw);
  s16*    pr1a = (s16*)(ws + o_part);
  s16*    pr1b = pr1a + 2048;
  s16*    pr1s = pr1b + 4096;
  s16*    pr2a = pr1s + 2048;
  s16*    pr2b = pr2a + 16384;
  s16*    pr2s = pr2b + 16384;

  zero_kernel<<<2, 256, 0, stream>>>(g2, 384);
  packw_kernel<<<11*32, 64, 0, stream>>>(fusew, pfw, 512);
  packw_kernel<<<16*32, 64, 0, stream>>>(attw, paw, 512);
  packw_kernel<<<1*4,  64, 0, stream>>>(r1aw, pr1a, 64);
  packw_kernel<<<2*4,  64, 0, stream>>>(r1bw, pr1b, 64);
  packw_kernel<<<1*4,  64, 0, stream>>>(r1sw, pr1s, 64);
  packw_kernel<<<4*8,  64, 0, stream>>>(r2aw, pr2a, 128);
  packw_kernel<<<4*8,  64, 0, stream>>>(r2bw, pr2b, 128);
  packw_kernel<<<4*8,  64, 0, stream>>>(r2sw, pr2s, 128);
  pad4_kernel<<<NPTS/256, 256, 0, stream>>>(pts, pts4);
  knn_kernel<<<NPTS, 256, 0, stream>>>(pts, pts4, knn);
  nbr_kernel<<<NPTS*16/256, 256, 0, stream>>>(pts, knn, na1w1, na1b1, na1w2, na1b2,
                                              na2w, na2b, na3w, na3b, ftr1);
  resblock_mfma<32,64><<<NPTS/64, 512, 0, stream>>>(ftr1, 32, nullptr, 0,
                                                    pr1a, r1ab, pr1b, r1bb, pr1s, r1sb, ftr2);
  colmax_kernel<<<dim3(32,2), 256, 0, stream>>>(ftr2, g2, 64);
  resblock_mfma<128,128><<<NPTS/64, 512, 0, stream>>>(ftr2, 64, g2, 1,
                                                      pr2a, r2ab, pr2b, r2bb, pr2s, r2sb, ftr3);
  colmax_kernel<<<dim3(32,2), 256, 0, stream>>>(ftr3, g3, 128);
  fuseatt_mfma<<<NPTS/64, 512, 0, stream>>>(ftr1, ftr2, ftr3, g3,
                                            pfw, fuseb, paw, attb, part);
  attmerge1_kernel<<<dim3(16,2), 512, 0, stream>>>(part, part2);
  attmerge2_kernel<<<4, 256, 0, stream>>>(part2, feat);
  headinit_kernel<<<4, 256, 0, stream>>>(fc1b, h1, 512);
  headpart_kernel<<<dim3(8, 8),  256, 0, stream>>>(feat, fc1w, h1, 1024, 512, 0);
  headinit_kernel<<<8, 256, 0, stream>>>(fc2b, h2, 1024);
  headpart_kernel<<<dim3(16, 4), 256, 0, stream>>>(h1, fc2w, h2, 512, 1024, 1);
  headinit_kernel<<<8, 256, 0, stream>>>(fc3b, (float*)d_out, 1024);
  headpart_kernel<<<dim3(16, 8), 256, 0, stream>>>(h2, fc3w, (float*)d_out, 1024, 1024, 1);
}

// Round 19
// 265.153 us; speedup vs baseline: 1.2989x; 1.0892x over previous
//
#include <hip/hip_runtime.h>
#include <math.h>

#define BB 2
#define NN 8192
#define NPTS (BB*NN)

typedef unsigned long long u64;
typedef short s16;
typedef __attribute__((ext_vector_type(8))) short short8v;
typedef __attribute__((ext_vector_type(4))) float f32x4;

__device__ __forceinline__ unsigned short f2bf(float v){
  unsigned u = __float_as_uint(v);
  return (unsigned short)((u + 0x7FFFu + ((u >> 16) & 1u)) >> 16);
}
__device__ __forceinline__ float bf2f(unsigned short h){
  return __uint_as_float(((unsigned)h) << 16);
}

// ------- packw helper: W[K,J] f32 -> bf16 MFMA B-fragment order (validated layout) -------
__device__ __forceinline__ void packw_job(const float* __restrict__ W, s16* __restrict__ out,
                                          int J, int blk, int lane){
  int ntb = J >> 4;
  int kt = blk / ntb, nt = blk % ntb;
  int k0 = kt*32 + ((lane>>4)<<3);
  int n  = nt*16 + (lane & 15);
  s16 v[8];
  #pragma unroll
  for (int i=0;i<8;++i) v[i] = (s16)f2bf(W[(size_t)(k0+i)*J + n]);
  *(short8v*)(out + (((size_t)blk)*64 + lane)*8) = *(short8v*)v;
}

// ---- fused prep: 8 packw jobs + pad4 + zero(g2,g3) + 3 head bias inits, one launch ----
// block budget (64 thr each): A fusew 352 | B attw 512 | C r1a 4 | D r1b 8 | E r1s 4
//                             F r2a 32 | G r2b 32 | H r2s 32 | I pad4 256 | J zero 6
//                             K h1 16 | L h2 32 | M dout 32   => 1318 blocks
__global__ __launch_bounds__(64) void prep_kernel(
    const float* __restrict__ fusew, s16* __restrict__ pfw,
    const float* __restrict__ attw,  s16* __restrict__ paw,
    const float* __restrict__ r1aw,  s16* __restrict__ pr1a,
    const float* __restrict__ r1bw,  s16* __restrict__ pr1b,
    const float* __restrict__ r1sw,  s16* __restrict__ pr1s,
    const float* __restrict__ r2aw,  s16* __restrict__ pr2a,
    const float* __restrict__ r2bw,  s16* __restrict__ pr2b,
    const float* __restrict__ r2sw,  s16* __restrict__ pr2s,
    const float* __restrict__ pts,   float4* __restrict__ pts4,
    float* __restrict__ g2,          // zeroes 384 floats (g2+g3)
    const float* __restrict__ fc1b,  float* __restrict__ h1,
    const float* __restrict__ fc2b,  float* __restrict__ h2,
    const float* __restrict__ fc3b,  float* __restrict__ dout)
{
  const int lane = threadIdx.x;
  int b = blockIdx.x;
  if (b < 352){ packw_job(fusew, pfw, 512, b, lane); return; }  b -= 352;
  if (b < 512){ packw_job(attw,  paw, 512, b, lane); return; }  b -= 512;
  if (b < 4)  { packw_job(r1aw, pr1a,  64, b, lane); return; }  b -= 4;
  if (b < 8)  { packw_job(r1bw, pr1b,  64, b, lane); return; }  b -= 8;
  if (b < 4)  { packw_job(r1sw, pr1s,  64, b, lane); return; }  b -= 4;
  if (b < 32) { packw_job(r2aw, pr2a, 128, b, lane); return; }  b -= 32;
  if (b < 32) { packw_job(r2bw, pr2b, 128, b, lane); return; }  b -= 32;
  if (b < 32) { packw_job(r2sw, pr2s, 128, b, lane); return; }  b -= 32;
  if (b < 256){
    int i = b*64 + lane;
    if (i < NPTS) pts4[i] = make_float4(pts[(size_t)i*3], pts[(size_t)i*3+1], pts[(size_t)i*3+2], 0.f);
    return;
  }  b -= 256;
  if (b < 6)  { int i = b*64 + lane; if (i < 384) g2[i] = 0.f; return; }  b -= 6;
  if (b < 16) { int i = b*64 + lane; if (i < 1024) h1[i]  = fc1b[i >= 512 ? i - 512 : i];   return; }  b -= 16;
  if (b < 32) { int i = b*64 + lane; if (i < 2048) h2[i]  = fc2b[i >= 1024 ? i - 1024 : i]; return; }  b -= 32;
  {             int i = b*64 + lane; if (i < 2048) dout[i] = fc3b[i >= 1024 ? i - 1024 : i]; return; }
}

// ---------------- KNN helpers: f32 branchless bitonic primitives (validated) ----------------
__device__ __forceinline__ void fce(float& a, float& b){
  float lo = fminf(a, b), hi = fmaxf(a, b);
  a = lo; b = hi;
}

__device__ __forceinline__ void bclean16f(float e[16]){
  #pragma unroll
  for (int i=0;i<8;++i) fce(e[i], e[i+8]);
  #pragma unroll
  for (int g=0; g<2; ++g){
    #pragma unroll
    for (int i=0;i<4;++i) fce(e[g*8+i], e[g*8+i+4]);
  }
  #pragma unroll
  for (int g=0; g<4; ++g){
    #pragma unroll
    for (int i=0;i<2;++i) fce(e[g*4+i], e[g*4+i+2]);
  }
  #pragma unroll
  for (int g=0; g<8; ++g) fce(e[g*2], e[g*2+1]);
}

__device__ __forceinline__ void clean8f(float A[8]){
  fce(A[0],A[4]); fce(A[1],A[5]); fce(A[2],A[6]); fce(A[3],A[7]);
  fce(A[0],A[2]); fce(A[1],A[3]); fce(A[4],A[6]); fce(A[5],A[7]);
  fce(A[0],A[1]); fce(A[2],A[3]); fce(A[4],A[5]); fce(A[6],A[7]);
}

__device__ __forceinline__ void merge_keep16f(float e[16], int maskXor){
  float p[16];
  #pragma unroll
  for (int i=0;i<16;++i) p[i] = __shfl_xor(e[i], maskXor);
  #pragma unroll
  for (int i=0;i<16;++i){ float o = p[15-i]; e[i] = fminf(e[i], o); }
  bclean16f(e);
}

// ---- KNN v7 (validated, 111us): dist-only scan (register-cached) + f32 threshold +
//      count-verified collection ----
__global__ __launch_bounds__(256) void knn_kernel(const float* __restrict__ pts,
                                                  const float4* __restrict__ pts4,
                                                  int* __restrict__ knn){
  __shared__ float poold[1024];           // [slot 0..15][col 0..63]
  __shared__ float ldsT;
  __shared__ int   cnt;
  __shared__ int   list[16];
  const int tid  = threadIdx.x;
  const int wid  = tid >> 6;
  const int lane = tid & 63;
  const int point = blockIdx.x;
  const int b = point >> 13;
  const int n = point & (NN-1);
  const float4* pb4 = pts4 + (size_t)b*NN;
  const float4 self = pb4[n];
  const float px = self.x, py = self.y, pz = self.z;

  float dcache[32];
  float d0=INFINITY, d1=INFINITY, d2=INFINITY, d3=INFINITY;
  const int mbase = wid*2048 + lane;
  #pragma unroll
  for (int t = 0; t < 32; ++t){
    int m = mbase + t*64;
    float4 q = pb4[m];
    float dx = q.x - px, dy = q.y - py, dz = q.z - pz;
    float dist = dx*dx + dy*dy + dz*dz;
    dist = (m == n) ? INFINITY : dist;
    dcache[t] = dist;
    float n3 = __builtin_amdgcn_fmed3f(dist, d2, d3);
    float n2 = __builtin_amdgcn_fmed3f(dist, d1, d2);
    float n1 = __builtin_amdgcn_fmed3f(dist, d0, d1);
    float n0 = fminf(dist, d0);
    d3=n3; d2=n2; d1=n1; d0=n0;
  }

  {
    const int j = tid & 3, col = tid >> 2;
    poold[(j*4+0)*64 + col] = d0;
    poold[(j*4+1)*64 + col] = d1;
    poold[(j*4+2)*64 + col] = d2;
    poold[(j*4+3)*64 + col] = d3;
  }
  if (tid == 0) cnt = 0;
  __syncthreads();

  if (wid == 0){
    float r[16];
    #pragma unroll
    for (int s=0;s<16;++s) r[s] = poold[s*64 + lane];
    float A[8] = {r[0],r[1],r[2],r[3],r[7],r[6],r[5],r[4]};
    clean8f(A);
    float B[8] = {r[8],r[9],r[10],r[11],r[15],r[14],r[13],r[12]};
    clean8f(B);
    float e[16];
    e[0]=A[0]; e[1]=A[1]; e[2]=A[2]; e[3]=A[3]; e[4]=A[4]; e[5]=A[5]; e[6]=A[6]; e[7]=A[7];
    e[8]=B[7]; e[9]=B[6]; e[10]=B[5]; e[11]=B[4]; e[12]=B[3]; e[13]=B[2]; e[14]=B[1]; e[15]=B[0];
    bclean16f(e);
    merge_keep16f(e, 1);
    merge_keep16f(e, 2);
    merge_keep16f(e, 4);
    merge_keep16f(e, 8);
    merge_keep16f(e, 16);
    merge_keep16f(e, 32);
    if (lane == 0) ldsT = e[15];
  }
  __syncthreads();
  const float T = ldsT;

  #pragma unroll
  for (int t = 0; t < 32; ++t){
    if (dcache[t] <= T){
      int p = atomicAdd(&cnt, 1);
      if (p < 16) list[p] = mbase + t*64;
    }
  }
  __syncthreads();

  if (cnt == 16){
    if (tid < 16) knn[(size_t)point*16 + tid] = list[tid];
    return;
  }
  if (wid != 0) return;

  const float* pb = pts + (size_t)b*NN*3;
  float d[16]; int id[16];
  #pragma unroll
  for (int j=0;j<16;++j){ d[j]=INFINITY; id[j]=0x7fffffff; }
  for (int m = lane; m < NN; m += 64){
    if (m == n) continue;
    float dx = pb[(size_t)m*3+0] - px;
    float dy = pb[(size_t)m*3+1] - py;
    float dz = pb[(size_t)m*3+2] - pz;
    float dist = dx*dx + dy*dy + dz*dz;
    if (dist < d[15] || (dist == d[15] && m < id[15])){
      float cd = dist; int ci = m;
      #pragma unroll
      for (int j=0;j<16;++j){
        bool sw = (cd < d[j]) || (cd == d[j] && ci < id[j]);
        float td = sw ? d[j] : cd; int ti = sw ? id[j] : ci;
        d[j]  = sw ? cd : d[j];
        id[j] = sw ? ci : id[j];
        cd = td; ci = ti;
      }
    }
  }
  for (int r=0; r<16; ++r){
    float bd = d[0]; int bi = id[0];
    for (int off=32; off>=1; off>>=1){
      float od = __shfl_xor(bd, off);
      int   oi = __shfl_xor(bi, off);
      bool take = (od < bd) || (od == bd && oi < bi);
      bd = take ? od : bd; bi = take ? oi : bi;
    }
    if (d[0] == bd && id[0] == bi){
      knn[(size_t)point*16 + r] = bi;
      #pragma unroll
      for (int j=0;j<15;++j){ d[j]=d[j+1]; id[j]=id[j+1]; }
      d[15]=INFINITY; id[15]=0x7fffffff;
    }
  }
}

// ------------- neighbor MLP + pool + ftr_1 (thread = point*16+k) -------------
__global__ __launch_bounds__(256) void nbr_kernel(
    const float* __restrict__ pts, const int* __restrict__ knn,
    const float* __restrict__ w1, const float* __restrict__ b1,
    const float* __restrict__ w2, const float* __restrict__ b2,
    const float* __restrict__ wp, const float* __restrict__ bp,
    const float* __restrict__ w3, const float* __restrict__ b3,
    float* __restrict__ ftr1)
{
  __shared__ float sw1[7*16], sb1[16], sw2[16*32], sb2[32], swp[3*32], sbp[32], sw3[64*32], sb3[32];
  for (int t = threadIdx.x; t < 7*16;  t += 256) sw1[t] = w1[t];
  for (int t = threadIdx.x; t < 16;    t += 256) sb1[t] = b1[t];
  for (int t = threadIdx.x; t < 16*32; t += 256) sw2[t] = w2[t];
  for (int t = threadIdx.x; t < 32;    t += 256) sb2[t] = b2[t];
  for (int t = threadIdx.x; t < 3*32;  t += 256) swp[t] = wp[t];
  for (int t = threadIdx.x; t < 32;    t += 256) sbp[t] = bp[t];
  for (int t = threadIdx.x; t < 64*32; t += 256) sw3[t] = w3[t];
  for (int t = threadIdx.x; t < 32;    t += 256) sb3[t] = b3[t];
  __syncthreads();
  int gt = blockIdx.x*256 + threadIdx.x;
  int point = gt >> 4;
  int k = gt & 15;
  int b = point >> 13;
  float ax = pts[(size_t)point*3+0];
  float ay = pts[(size_t)point*3+1];
  float az = pts[(size_t)point*3+2];
  int idx = knn[(size_t)point*16 + k] & (NN-1);
  size_t nb = ((size_t)b*NN + idx)*3;
  float rx = pts[nb+0] - ax;
  float ry = pts[nb+1] - ay;
  float rz = pts[nb+2] - az;
  float dd = sqrtf(rx*rx + ry*ry + rz*rz + 1e-8f);
  float in7[7] = {ax, ay, az, rx, ry, rz, dd};
  float h16[16];
  #pragma unroll
  for (int j=0;j<16;++j){
    float a = sb1[j];
    #pragma unroll
    for (int c=0;c<7;++c) a += in7[c]*sw1[c*16+j];
    h16[j] = fmaxf(a, 0.f);
  }
  float h32[32];
  #pragma unroll
  for (int j=0;j<32;++j){
    float a = sb2[j];
    #pragma unroll
    for (int c=0;c<16;++c) a += h16[c]*sw2[c*32+j];
    h32[j] = fmaxf(a, 0.f);
  }
  #pragma unroll
  for (int j=0;j<32;++j){
    h32[j] = fmaxf(h32[j], __shfl_xor(h32[j], 8));
    h32[j] = fmaxf(h32[j], __shfl_xor(h32[j], 4));
    h32[j] = fmaxf(h32[j], __shfl_xor(h32[j], 2));
    h32[j] = fmaxf(h32[j], __shfl_xor(h32[j], 1));
  }
  if (k == 0){
    float lift[32];
    #pragma unroll
    for (int j=0;j<32;++j){
      float a = sbp[j] + ax*swp[0*32+j] + ay*swp[1*32+j] + az*swp[2*32+j];
      lift[j] = fmaxf(a, 0.f);
    }
    #pragma unroll
    for (int j=0;j<32;++j){
      float a = sb3[j];
      #pragma unroll
      for (int c=0;c<32;++c) a += lift[c]*sw3[c*32+j];
      #pragma unroll
      for (int c=0;c<32;++c) a += h32[c]*sw3[(32+c)*32+j];
      ftr1[(size_t)point*32 + j] = fmaxf(a, 0.f);
    }
  }
}

// ------------- column max over N per batch -------------
__global__ __launch_bounds__(256) void colmax_kernel(const float* __restrict__ X, float* __restrict__ out, int J){
  int b  = blockIdx.y;
  int n0 = blockIdx.x * 256;
  int f  = threadIdx.x % J;
  int r0 = threadIdx.x / J;
  int step = 256 / J;
  float vm = 0.f;
  for (int n = n0 + r0; n < n0 + 256; n += step)
    vm = fmaxf(vm, X[((size_t)b*NN + n)*J + f]);
  atomicMax((int*)&out[b*J + f], __float_as_int(vm));
}

// ------- online-softmax pairwise merge -------
__device__ __forceinline__ void omerge(float& m, float& s, float& a, float& f,
                                       float m2, float s2, float a2, float f2){
  float mn = fmaxf(m, m2);
  float e1 = __expf(m - mn), e2 = __expf(m2 - mn);
  s = s*e1 + s2*e2;
  a = a*e1 + a2*e2;
  m = mn;
  f = fmaxf(f, f2);
}

// ---- MFMA residual SMLP: Y = relu( relu(X@wa+ba)@wb + bb + X@ws + bs ) ----
template<int KIN, int JM>
__global__ __launch_bounds__(512) void resblock_mfma(
    const float* __restrict__ s0, int w0,
    const float* __restrict__ s1, int bc1,
    const s16* __restrict__ pwa, const float* __restrict__ ba,
    const s16* __restrict__ pwb, const float* __restrict__ bb,
    const s16* __restrict__ pws, const float* __restrict__ bs,
    float* __restrict__ Y)
{
  constexpr int XP  = KIN + 8;
  constexpr int AP  = JM + 8;
  constexpr int NTB = JM/16;
  constexpr int NTW = NTB/2;
  constexpr int KT1 = KIN/32;
  constexpr int KT2 = JM/32;
  __shared__ s16 xs[64*XP];
  __shared__ s16 as_[64*AP];
  const int tid  = threadIdx.x;
  const int lane = tid & 63;
  const int w    = tid >> 6;
  const int mt   = w >> 1;
  const int half = w & 1;
  const int l15  = lane & 15;
  const int lk   = lane >> 4;
  const int n0   = blockIdx.x * 64;

  for (int t = tid; t < 64*KIN; t += 512){
    int r = t / KIN, c = t - r*KIN;
    int row = n0 + r;
    float v = (c < w0) ? s0[(size_t)row*w0 + c]
                       : s1[(size_t)(bc1 ? (row>>13) : row)*(KIN-w0) + (c-w0)];
    xs[r*XP + c] = (s16)f2bf(v);
  }
  __syncthreads();

  {
    const s16* arow = xs + (mt*16 + l15)*XP + lk*8;
    const int rb = mt*16 + lk*4;
    #pragma unroll
    for (int ntg = 0; ntg < NTW; ++ntg){
      const int ntA = half*NTW + ntg;
      f32x4 acc = {0.f,0.f,0.f,0.f};
      #pragma unroll
      for (int kt = 0; kt < KT1; ++kt){
        short8v a = *(const short8v*)(arow + kt*32);
        short8v bfr = *(const short8v*)(pwa + (((size_t)kt*NTB + ntA)*64 + lane)*8);
        acc = __builtin_amdgcn_mfma_f32_16x16x32_bf16(a, bfr, acc, 0, 0, 0);
      }
      const int col = ntA*16 + l15;
      const float bv = ba[col];
      #pragma unroll
      for (int r=0;r<4;++r)
        as_[(rb+r)*AP + col] = (s16)f2bf(fmaxf(acc[r] + bv, 0.f));
    }
  }
  __syncthreads();

  {
    const s16* arowA = as_ + (mt*16 + l15)*AP + lk*8;
    const s16* arowX = xs  + (mt*16 + l15)*XP + lk*8;
    const int rb = mt*16 + lk*4;
    #pragma unroll
    for (int ntg = 0; ntg < NTW; ++ntg){
      const int ntA = half*NTW + ntg;
      f32x4 acc = {0.f,0.f,0.f,0.f};
      #pragma unroll
      for (int kt = 0; kt < KT2; ++kt){
        short8v a = *(const short8v*)(arowA + kt*32);
        short8v bfr = *(const short8v*)(pwb + (((size_t)kt*NTB + ntA)*64 + lane)*8);
        acc = __builtin_amdgcn_mfma_f32_16x16x32_bf16(a, bfr, acc, 0, 0, 0);
      }
      #pragma unroll
      for (int kt = 0; kt < KT1; ++kt){
        short8v a = *(const short8v*)(arowX + kt*32);
        short8v bfr = *(const short8v*)(pws + (((size_t)kt*NTB + ntA)*64 + lane)*8);
        acc = __builtin_amdgcn_mfma_f32_16x16x32_bf16(a, bfr, acc, 0, 0, 0);
      }
      const int col = ntA*16 + l15;
      const float bv = bb[col] + bs[col];
      #pragma unroll
      for (int r=0;r<4;++r)
        Y[(size_t)(n0 + rb + r)*JM + col] = fmaxf(acc[r] + bv, 0.f);
    }
  }
}

// ---- MFMA fused fuse-GEMM + att-GEMM + online softmax partials ----
__global__ __launch_bounds__(512) void fuseatt_mfma(
    const float* __restrict__ f1, const float* __restrict__ f2,
    const float* __restrict__ f3, const float* __restrict__ g3,
    const s16* __restrict__ pfw, const float* __restrict__ fb,
    const s16* __restrict__ paw, const float* __restrict__ ab,
    float4* __restrict__ part)
{
  __shared__ __align__(16) char arena[112640];
  s16*   f4s = (s16*)arena;                 // [64][520] bf16 ftr4 tile
  s16*   xs  = (s16*)(arena + 66560);       // [64][360] bf16 input tile
  float4* pb = (float4*)(arena + 66560);    // [4 mt][512 col] partials (aliases xs)
  const int chunk = blockIdx.x;
  const int tid  = threadIdx.x;
  const int lane = tid & 63;
  const int w    = tid >> 6;
  const int mt   = w >> 1;
  const int half = w & 1;
  const int l15  = lane & 15;
  const int lk   = lane >> 4;
  const int n0   = chunk*64;

  for (int t = tid; t < 64*352; t += 512){
    int r = t / 352, c = t - r*352;
    int row = n0 + r;
    float v;
    if (c < 32)       v = f1[(size_t)row*32 + c];
    else if (c < 96)  v = f2[(size_t)row*64 + (c-32)];
    else if (c < 224) v = f3[(size_t)row*128 + (c-96)];
    else              v = g3[(size_t)(row>>13)*128 + (c-224)];
    xs[r*360 + c] = (s16)f2bf(v);
  }
  __syncthreads();

  {
    const s16* arow = xs + (mt*16 + l15)*360 + lk*8;
    const int rb = mt*16 + lk*4;
    for (int ntg = 0; ntg < 16; ntg += 4){
      const int ntA = half*16 + ntg;
      f32x4 acc0={0,0,0,0}, acc1={0,0,0,0}, acc2={0,0,0,0}, acc3={0,0,0,0};
      for (int kt = 0; kt < 11; ++kt){
        short8v a = *(const short8v*)(arow + kt*32);
        const s16* bp = pfw + (((size_t)kt*32 + ntA)*64 + lane)*8;
        short8v b0 = *(const short8v*)(bp);
        short8v b1 = *(const short8v*)(bp + 512);
        short8v b2 = *(const short8v*)(bp + 1024);
        short8v b3 = *(const short8v*)(bp + 1536);
        acc0 = __builtin_amdgcn_mfma_f32_16x16x32_bf16(a, b0, acc0, 0, 0, 0);
        acc1 = __builtin_amdgcn_mfma_f32_16x16x32_bf16(a, b1, acc1, 0, 0, 0);
        acc2 = __builtin_amdgcn_mfma_f32_16x16x32_bf16(a, b2, acc2, 0, 0, 0);
        acc3 = __builtin_amdgcn_mfma_f32_16x16x32_bf16(a, b3, acc3, 0, 0, 0);
      }
      #define FUSE_EPI(ACC, J) { \
        int col = (ntA + (J))*16 + l15; float bv = fb[col]; \
        f4s[(rb+0)*520 + col] = (s16)f2bf(fmaxf(ACC[0] + bv, 0.f)); \
        f4s[(rb+1)*520 + col] = (s16)f2bf(fmaxf(ACC[1] + bv, 0.f)); \
        f4s[(rb+2)*520 + col] = (s16)f2bf(fmaxf(ACC[2] + bv, 0.f)); \
        f4s[(rb+3)*520 + col] = (s16)f2bf(fmaxf(ACC[3] + bv, 0.f)); }
      FUSE_EPI(acc0, 0) FUSE_EPI(acc1, 1) FUSE_EPI(acc2, 2) FUSE_EPI(acc3, 3)
      #undef FUSE_EPI
    }
  }
  __syncthreads();

  {
    const s16* arow = f4s + (mt*16 + l15)*520 + lk*8;
    const int rb = mt*16 + lk*4;
    for (int ntg = 0; ntg < 16; ntg += 4){
      const int ntA = half*16 + ntg;
      f32x4 acc0={0,0,0,0}, acc1={0,0,0,0}, acc2={0,0,0,0}, acc3={0,0,0,0};
      for (int kt = 0; kt < 16; ++kt){
        short8v a = *(const short8v*)(arow + kt*32);
        const s16* bp = paw + (((size_t)kt*32 + ntA)*64 + lane)*8;
        short8v b0 = *(const short8v*)(bp);
        short8v b1 = *(const short8v*)(bp + 512);
        short8v b2 = *(const short8v*)(bp + 1024);
        short8v b3 = *(const short8v*)(bp + 1536);
        acc0 = __builtin_amdgcn_mfma_f32_16x16x32_bf16(a, b0, acc0, 0, 0, 0);
        acc1 = __builtin_amdgcn_mfma_f32_16x16x32_bf16(a, b1, acc1, 0, 0, 0);
        acc2 = __builtin_amdgcn_mfma_f32_16x16x32_bf16(a, b2, acc2, 0, 0, 0);
        acc3 = __builtin_amdgcn_mfma_f32_16x16x32_bf16(a, b3, acc3, 0, 0, 0);
      }
      #define ATT_EPI(ACC, J) { \
        int col = (ntA + (J))*16 + l15; float lb = ab[col]; \
        float m_ = -INFINITY, s_ = 0.f, a_ = 0.f, fx_ = 0.f; \
        _Pragma("unroll") \
        for (int r = 0; r < 4; ++r){ \
          float lv = ACC[r] + lb; \
          float x  = bf2f((unsigned short)f4s[(rb+r)*520 + col]); \
          float mn = fmaxf(m_, lv); \
          float e0 = __expf(m_ - mn), e1 = __expf(lv - mn); \
          s_ = s_*e0 + e1; a_ = a_*e0 + x*e1; m_ = mn; fx_ = fmaxf(fx_, x); \
        } \
        { float om = __shfl_xor(m_,16), os = __shfl_xor(s_,16), oa = __shfl_xor(a_,16), of = __shfl_xor(fx_,16); \
          omerge(m_, s_, a_, fx_, om, os, oa, of); } \
        { float om = __shfl_xor(m_,32), os = __shfl_xor(s_,32), oa = __shfl_xor(a_,32), of = __shfl_xor(fx_,32); \
          omerge(m_, s_, a_, fx_, om, os, oa, of); } \
        if (lk == 0) pb[mt*512 + col] = make_float4(m_, s_, a_, fx_); }
      ATT_EPI(acc0, 0) ATT_EPI(acc1, 1) ATT_EPI(acc2, 2) ATT_EPI(acc3, 3)
      #undef ATT_EPI
    }
  }
  __syncthreads();

  {
    float4 p0 = pb[tid], p1 = pb[512 + tid], p2 = pb[1024 + tid], p3 = pb[1536 + tid];
    float m_ = p0.x, s_ = p0.y, a_ = p0.z, f_ = p0.w;
    omerge(m_, s_, a_, f_, p1.x, p1.y, p1.z, p1.w);
    omerge(m_, s_, a_, f_, p2.x, p2.y, p2.z, p2.w);
    omerge(m_, s_, a_, f_, p3.x, p3.y, p3.z, p3.w);
    part[(size_t)chunk*512 + tid] = make_float4(m_, s_, a_, f_);
  }
}

// ---- two-stage attention merge ----
__global__ __launch_bounds__(512) void attmerge1_kernel(const float4* __restrict__ part, float4* __restrict__ part2){
  int g = blockIdx.x;
  int b = blockIdx.y;
  int f = threadIdx.x;
  float m=-INFINITY, s=0.f, a=0.f, fx=0.f;
  for (int c = g*8; c < g*8+8; ++c){
    float4 p = part[((size_t)(b*128 + c))*512 + f];
    omerge(m, s, a, fx, p.x, p.y, p.z, p.w);
  }
  part2[((size_t)(b*16 + g))*512 + f] = make_float4(m, s, a, fx);
}

__global__ __launch_bounds__(256) void attmerge2_kernel(const float4* __restrict__ part2, float* __restrict__ feat){
  int t = blockIdx.x*256 + threadIdx.x;
  if (t >= BB*512) return;
  int b = t >> 9, f = t & 511;
  float m=-INFINITY, s=0.f, a=0.f, fx=0.f;
  for (int c=0;c<16;++c){
    float4 p = part2[((size_t)(b*16 + c))*512 + f];
    omerge(m, s, a, fx, p.x, p.y, p.z, p.w);
  }
  feat[(size_t)b*1024 + f] = fx;
  feat[(size_t)b*1024 + 512 + f] = a / s;
}

// ------------- head MLP: split-K atomic partials (Y pre-initialized with bias in prep) -------------
__global__ __launch_bounds__(256) void headpart_kernel(
    const float* __restrict__ X, const float* __restrict__ W, float* __restrict__ Y,
    int K, int J, int relu_in)
{
  const int j  = blockIdx.x*64 + (threadIdx.x & 63);
  const int k0 = blockIdx.y*128 + (threadIdx.x >> 6)*32;
  float acc0 = 0.f, acc1 = 0.f;
  #pragma unroll 8
  for (int k = 0; k < 32; ++k){
    float x0 = X[k0+k], x1 = X[K + k0+k];
    if (relu_in){ x0 = fmaxf(x0, 0.f); x1 = fmaxf(x1, 0.f); }
    float w = W[(size_t)(k0+k)*J + j];
    acc0 += x0*w; acc1 += x1*w;
  }
  atomicAdd(&Y[j], acc0);
  atomicAdd(&Y[J+j], acc1);
}

extern "C" void kernel_launch(void* const* d_in, const int* in_sizes, int n_in,
                              void* d_out, int out_size, void* d_ws, size_t ws_size,
                              hipStream_t stream)
{
  const float* pts    = (const float*)d_in[0];
  const float* na1w1  = (const float*)d_in[1];
  const float* na1b1  = (const float*)d_in[2];
  const float* na1w2  = (const float*)d_in[3];
  const float* na1b2  = (const float*)d_in[4];
  const float* na2w   = (const float*)d_in[5];
  const float* na2b   = (const float*)d_in[6];
  const float* na3w   = (const float*)d_in[7];
  const float* na3b   = (const float*)d_in[8];
  const float* r1aw   = (const float*)d_in[9];
  const float* r1ab   = (const float*)d_in[10];
  const float* r1bw   = (const float*)d_in[11];
  const float* r1bb   = (const float*)d_in[12];
  const float* r1sw   = (const float*)d_in[13];
  const float* r1sb   = (const float*)d_in[14];
  const float* r2aw   = (const float*)d_in[15];
  const float* r2ab   = (const float*)d_in[16];
  const float* r2bw   = (const float*)d_in[17];
  const float* r2bb   = (const float*)d_in[18];
  const float* r2sw   = (const float*)d_in[19];
  const float* r2sb   = (const float*)d_in[20];
  const float* fusew  = (const float*)d_in[21];
  const float* fuseb  = (const float*)d_in[22];
  const float* attw   = (const float*)d_in[23];
  const float* attb   = (const float*)d_in[24];
  const float* fc1w   = (const float*)d_in[25];
  const float* fc1b   = (const float*)d_in[26];
  const float* fc2w   = (const float*)d_in[27];
  const float* fc2b   = (const float*)d_in[28];
  const float* fc3w   = (const float*)d_in[29];
  const float* fc3b   = (const float*)d_in[30];

  if (n_in < 31) return;
  if (in_sizes[0] != NPTS*3) return;
  if (in_sizes[21] != 352*512) return;
  if (in_sizes[29] != 1024*1024) return;

  // Workspace layout (float offsets).
  const size_t o_ftr1 = 0;
  const size_t o_ftr2 = 524288;
  const size_t o_ftr3 = 1572864;
  const size_t o_knn  = 1572864;
  const size_t o_part = 3670016;
  const size_t o_g2   = 4194304;
  const size_t o_g3   = 4194432;
  const size_t o_feat = 4194688;
  const size_t o_h1   = 4196736;
  const size_t o_h2   = 4197760;
  const size_t o_pfw  = 4199808;
  const size_t o_paw  = o_pfw + 90112;
  const size_t mfma_bytes = 4420992ull * 4ull;
  if (ws_size < mfma_bytes) return;

  float* ws = (float*)d_ws;
  float*  ftr1  = ws + o_ftr1;
  float4* pts4  = (float4*)(ws + o_ftr1);
  float4* part2 = (float4*)(ws + o_ftr1);
  float*  ftr2 = ws + o_ftr2;
  float*  ftr3 = ws + o_ftr3;
  int*    knn  = (int*)(ws + o_knn);
  float4* part = (float4*)(ws + o_part);
  float*  g2   = ws + o_g2;
  float*  g3   = ws + o_g3;
  float*  feat = ws + o_feat;
  float*  h1   = ws + o_h1;
  float*  h2   = ws + o_h2;
  s16*    pfw  = (s16*)(ws + o_pfw);
  s16*    paw  = (s16*)(ws + o_paw);
  s16*    pr1a = (s16*)(ws + o_part);
  s16*    pr1b = pr1a + 2048;
  s16*    pr1s = pr1b + 4096;
  s16*    pr2a = pr1s + 2048;
  s16*    pr2b = pr2a + 16384;
  s16*    pr2s = pr2b + 16384;

  // 1. fused prep: packs + pad4 + zero(g2,g3) + head bias inits (13 launches -> 1)
  prep_kernel<<<1318, 64, 0, stream>>>(fusew, pfw, attw, paw,
                                       r1aw, pr1a, r1bw, pr1b, r1sw, pr1s,
                                       r2aw, pr2a, r2bw, pr2b, r2sw, pr2s,
                                       pts, pts4, g2,
                                       fc1b, h1, fc2b, h2, fc3b, (float*)d_out);
  // 2. main pipeline (unchanged)
  knn_kernel<<<NPTS, 256, 0, stream>>>(pts, pts4, knn);
  nbr_kernel<<<NPTS*16/256, 256, 0, stream>>>(pts, knn, na1w1, na1b1, na1w2, na1b2,
                                              na2w, na2b, na3w, na3b, ftr1);
  resblock_mfma<32,64><<<NPTS/64, 512, 0, stream>>>(ftr1, 32, nullptr, 0,
                                                    pr1a, r1ab, pr1b, r1bb, pr1s, r1sb, ftr2);
  colmax_kernel<<<dim3(32,2), 256, 0, stream>>>(ftr2, g2, 64);
  resblock_mfma<128,128><<<NPTS/64, 512, 0, stream>>>(ftr2, 64, g2, 1,
                                                      pr2a, r2ab, pr2b, r2bb, pr2s, r2sb, ftr3);
  colmax_kernel<<<dim3(32,2), 256, 0, stream>>>(ftr3, g3, 128);
  fuseatt_mfma<<<NPTS/64, 512, 0, stream>>>(ftr1, ftr2, ftr3, g3,
                                            pfw, fuseb, paw, attb, part);
  attmerge1_kernel<<<dim3(16,2), 512, 0, stream>>>(part, part2);
  attmerge2_kernel<<<4, 256, 0, stream>>>(part2, feat);
  headpart_kernel<<<dim3(8, 8),  256, 0, stream>>>(feat, fc1w, h1, 1024, 512, 0);
  headpart_kernel<<<dim3(16, 4), 256, 0, stream>>>(h1, fc2w, h2, 512, 1024, 1);
  headpart_kernel<<<dim3(16, 8), 256, 0, stream>>>(h2, fc3w, (float*)d_out, 1024, 1024, 1);
}

// Round 20
// 236.173 us; speedup vs baseline: 1.4583x; 1.1227x over previous
//
#include <hip/hip_runtime.h>
#include <math.h>

#define BB 2
#define NN 8192
#define NPTS (BB*NN)

typedef unsigned long long u64;
typedef short s16;
typedef __attribute__((ext_vector_type(8))) short short8v;
typedef __attribute__((ext_vector_type(4))) float f32x4;

__device__ __forceinline__ unsigned short f2bf(float v){
  unsigned u = __float_as_uint(v);
  return (unsigned short)((u + 0x7FFFu + ((u >> 16) & 1u)) >> 16);
}
__device__ __forceinline__ float bf2f(unsigned short h){
  return __uint_as_float(((unsigned)h) << 16);
}

// ------- packw helper: W[K,J] f32 -> bf16 MFMA B-fragment order (validated layout) -------
__device__ __forceinline__ void packw_job(const float* __restrict__ W, s16* __restrict__ out,
                                          int J, int blk, int lane){
  int ntb = J >> 4;
  int kt = blk / ntb, nt = blk % ntb;
  int k0 = kt*32 + ((lane>>4)<<3);
  int n  = nt*16 + (lane & 15);
  s16 v[8];
  #pragma unroll
  for (int i=0;i<8;++i) v[i] = (s16)f2bf(W[(size_t)(k0+i)*J + n]);
  *(short8v*)(out + (((size_t)blk)*64 + lane)*8) = *(short8v*)v;
}

// ---- fused prep: 8 packw jobs + pad4 + zero(g2,g3) + 3 head bias inits, one launch ----
__global__ __launch_bounds__(64) void prep_kernel(
    const float* __restrict__ fusew, s16* __restrict__ pfw,
    const float* __restrict__ attw,  s16* __restrict__ paw,
    const float* __restrict__ r1aw,  s16* __restrict__ pr1a,
    const float* __restrict__ r1bw,  s16* __restrict__ pr1b,
    const float* __restrict__ r1sw,  s16* __restrict__ pr1s,
    const float* __restrict__ r2aw,  s16* __restrict__ pr2a,
    const float* __restrict__ r2bw,  s16* __restrict__ pr2b,
    const float* __restrict__ r2sw,  s16* __restrict__ pr2s,
    const float* __restrict__ pts,   float4* __restrict__ pts4,
    float* __restrict__ g2,          // zeroes 384 floats (g2+g3)
    const float* __restrict__ fc1b,  float* __restrict__ h1,
    const float* __restrict__ fc2b,  float* __restrict__ h2,
    const float* __restrict__ fc3b,  float* __restrict__ dout)
{
  const int lane = threadIdx.x;
  int b = blockIdx.x;
  if (b < 352){ packw_job(fusew, pfw, 512, b, lane); return; }  b -= 352;
  if (b < 512){ packw_job(attw,  paw, 512, b, lane); return; }  b -= 512;
  if (b < 4)  { packw_job(r1aw, pr1a,  64, b, lane); return; }  b -= 4;
  if (b < 8)  { packw_job(r1bw, pr1b,  64, b, lane); return; }  b -= 8;
  if (b < 4)  { packw_job(r1sw, pr1s,  64, b, lane); return; }  b -= 4;
  if (b < 32) { packw_job(r2aw, pr2a, 128, b, lane); return; }  b -= 32;
  if (b < 32) { packw_job(r2bw, pr2b, 128, b, lane); return; }  b -= 32;
  if (b < 32) { packw_job(r2sw, pr2s, 128, b, lane); return; }  b -= 32;
  if (b < 256){
    int i = b*64 + lane;
    if (i < NPTS) pts4[i] = make_float4(pts[(size_t)i*3], pts[(size_t)i*3+1], pts[(size_t)i*3+2], 0.f);
    return;
  }  b -= 256;
  if (b < 6)  { int i = b*64 + lane; if (i < 384) g2[i] = 0.f; return; }  b -= 6;
  if (b < 16) { int i = b*64 + lane; if (i < 1024) h1[i]  = fc1b[i >= 512 ? i - 512 : i];   return; }  b -= 16;
  if (b < 32) { int i = b*64 + lane; if (i < 2048) h2[i]  = fc2b[i >= 1024 ? i - 1024 : i]; return; }  b -= 32;
  {             int i = b*64 + lane; if (i < 2048) dout[i] = fc3b[i >= 1024 ? i - 1024 : i]; return; }
}

// ---------------- KNN helpers: f32 branchless bitonic primitives (validated) ----------------
__device__ __forceinline__ void fce(float& a, float& b){
  float lo = fminf(a, b), hi = fmaxf(a, b);
  a = lo; b = hi;
}

__device__ __forceinline__ void bclean16f(float e[16]){
  #pragma unroll
  for (int i=0;i<8;++i) fce(e[i], e[i+8]);
  #pragma unroll
  for (int g=0; g<2; ++g){
    #pragma unroll
    for (int i=0;i<4;++i) fce(e[g*8+i], e[g*8+i+4]);
  }
  #pragma unroll
  for (int g=0; g<4; ++g){
    #pragma unroll
    for (int i=0;i<2;++i) fce(e[g*4+i], e[g*4+i+2]);
  }
  #pragma unroll
  for (int g=0; g<8; ++g) fce(e[g*2], e[g*2+1]);
}

__device__ __forceinline__ void clean8f(float A[8]){
  fce(A[0],A[4]); fce(A[1],A[5]); fce(A[2],A[6]); fce(A[3],A[7]);
  fce(A[0],A[2]); fce(A[1],A[3]); fce(A[4],A[6]); fce(A[5],A[7]);
  fce(A[0],A[1]); fce(A[2],A[3]); fce(A[4],A[5]); fce(A[6],A[7]);
}

__device__ __forceinline__ void merge_keep16f(float e[16], int maskXor){
  float p[16];
  #pragma unroll
  for (int i=0;i<16;++i) p[i] = __shfl_xor(e[i], maskXor);
  #pragma unroll
  for (int i=0;i<16;++i){ float o = p[15-i]; e[i] = fminf(e[i], o); }
  bclean16f(e);
}

// ---- KNN v7 (validated, 111us): dist-only scan (register-cached) + f32 threshold +
//      count-verified collection ----
__global__ __launch_bounds__(256) void knn_kernel(const float* __restrict__ pts,
                                                  const float4* __restrict__ pts4,
                                                  int* __restrict__ knn){
  __shared__ float poold[1024];           // [slot 0..15][col 0..63]
  __shared__ float ldsT;
  __shared__ int   cnt;
  __shared__ int   list[16];
  const int tid  = threadIdx.x;
  const int wid  = tid >> 6;
  const int lane = tid & 63;
  const int point = blockIdx.x;
  const int b = point >> 13;
  const int n = point & (NN-1);
  const float4* pb4 = pts4 + (size_t)b*NN;
  const float4 self = pb4[n];
  const float px = self.x, py = self.y, pz = self.z;

  float dcache[32];
  float d0=INFINITY, d1=INFINITY, d2=INFINITY, d3=INFINITY;
  const int mbase = wid*2048 + lane;
  #pragma unroll
  for (int t = 0; t < 32; ++t){
    int m = mbase + t*64;
    float4 q = pb4[m];
    float dx = q.x - px, dy = q.y - py, dz = q.z - pz;
    float dist = dx*dx + dy*dy + dz*dz;
    dist = (m == n) ? INFINITY : dist;
    dcache[t] = dist;
    float n3 = __builtin_amdgcn_fmed3f(dist, d2, d3);
    float n2 = __builtin_amdgcn_fmed3f(dist, d1, d2);
    float n1 = __builtin_amdgcn_fmed3f(dist, d0, d1);
    float n0 = fminf(dist, d0);
    d3=n3; d2=n2; d1=n1; d0=n0;
  }

  {
    const int j = tid & 3, col = tid >> 2;
    poold[(j*4+0)*64 + col] = d0;
    poold[(j*4+1)*64 + col] = d1;
    poold[(j*4+2)*64 + col] = d2;
    poold[(j*4+3)*64 + col] = d3;
  }
  if (tid == 0) cnt = 0;
  __syncthreads();

  if (wid == 0){
    float r[16];
    #pragma unroll
    for (int s=0;s<16;++s) r[s] = poold[s*64 + lane];
    float A[8] = {r[0],r[1],r[2],r[3],r[7],r[6],r[5],r[4]};
    clean8f(A);
    float B[8] = {r[8],r[9],r[10],r[11],r[15],r[14],r[13],r[12]};
    clean8f(B);
    float e[16];
    e[0]=A[0]; e[1]=A[1]; e[2]=A[2]; e[3]=A[3]; e[4]=A[4]; e[5]=A[5]; e[6]=A[6]; e[7]=A[7];
    e[8]=B[7]; e[9]=B[6]; e[10]=B[5]; e[11]=B[4]; e[12]=B[3]; e[13]=B[2]; e[14]=B[1]; e[15]=B[0];
    bclean16f(e);
    merge_keep16f(e, 1);
    merge_keep16f(e, 2);
    merge_keep16f(e, 4);
    merge_keep16f(e, 8);
    merge_keep16f(e, 16);
    merge_keep16f(e, 32);
    if (lane == 0) ldsT = e[15];
  }
  __syncthreads();
  const float T = ldsT;

  #pragma unroll
  for (int t = 0; t < 32; ++t){
    if (dcache[t] <= T){
      int p = atomicAdd(&cnt, 1);
      if (p < 16) list[p] = mbase + t*64;
    }
  }
  __syncthreads();

  if (cnt == 16){
    if (tid < 16) knn[(size_t)point*16 + tid] = list[tid];
    return;
  }
  if (wid != 0) return;

  const float* pb = pts + (size_t)b*NN*3;
  float d[16]; int id[16];
  #pragma unroll
  for (int j=0;j<16;++j){ d[j]=INFINITY; id[j]=0x7fffffff; }
  for (int m = lane; m < NN; m += 64){
    if (m == n) continue;
    float dx = pb[(size_t)m*3+0] - px;
    float dy = pb[(size_t)m*3+1] - py;
    float dz = pb[(size_t)m*3+2] - pz;
    float dist = dx*dx + dy*dy + dz*dz;
    if (dist < d[15] || (dist == d[15] && m < id[15])){
      float cd = dist; int ci = m;
      #pragma unroll
      for (int j=0;j<16;++j){
        bool sw = (cd < d[j]) || (cd == d[j] && ci < id[j]);
        float td = sw ? d[j] : cd; int ti = sw ? id[j] : ci;
        d[j]  = sw ? cd : d[j];
        id[j] = sw ? ci : id[j];
        cd = td; ci = ti;
      }
    }
  }
  for (int r=0; r<16; ++r){
    float bd = d[0]; int bi = id[0];
    for (int off=32; off>=1; off>>=1){
      float od = __shfl_xor(bd, off);
      int   oi = __shfl_xor(bi, off);
      bool take = (od < bd) || (od == bd && oi < bi);
      bd = take ? od : bd; bi = take ? oi : bi;
    }
    if (d[0] == bd && id[0] == bi){
      knn[(size_t)point*16 + r] = bi;
      #pragma unroll
      for (int j=0;j<15;++j){ d[j]=d[j+1]; id[j]=id[j+1]; }
      d[15]=INFINITY; id[15]=0x7fffffff;
    }
  }
}

// ------------- neighbor MLP + pool + ftr_1 v2: cooperative tail (thread = point*16+k) -------------
__global__ __launch_bounds__(256) void nbr_kernel(
    const float* __restrict__ pts, const int* __restrict__ knn,
    const float* __restrict__ w1, const float* __restrict__ b1,
    const float* __restrict__ w2, const float* __restrict__ b2,
    const float* __restrict__ wp, const float* __restrict__ bp,
    const float* __restrict__ w3, const float* __restrict__ b3,
    float* __restrict__ ftr1)
{
  __shared__ float sw1[7*16], sb1[16], sw2[16*32], sb2[32], swp[3*32], sbp[32], sw3[64*32], sb3[32];
  for (int t = threadIdx.x; t < 7*16;  t += 256) sw1[t] = w1[t];
  for (int t = threadIdx.x; t < 16;    t += 256) sb1[t] = b1[t];
  for (int t = threadIdx.x; t < 16*32; t += 256) sw2[t] = w2[t];
  for (int t = threadIdx.x; t < 32;    t += 256) sb2[t] = b2[t];
  for (int t = threadIdx.x; t < 3*32;  t += 256) swp[t] = wp[t];
  for (int t = threadIdx.x; t < 32;    t += 256) sbp[t] = bp[t];
  for (int t = threadIdx.x; t < 64*32; t += 256) sw3[t] = w3[t];
  for (int t = threadIdx.x; t < 32;    t += 256) sb3[t] = b3[t];
  __syncthreads();
  int gt = blockIdx.x*256 + threadIdx.x;
  int point = gt >> 4;
  int k = gt & 15;
  int b = point >> 13;
  float ax = pts[(size_t)point*3+0];
  float ay = pts[(size_t)point*3+1];
  float az = pts[(size_t)point*3+2];
  int idx = knn[(size_t)point*16 + k] & (NN-1);
  size_t nb = ((size_t)b*NN + idx)*3;
  float rx = pts[nb+0] - ax;
  float ry = pts[nb+1] - ay;
  float rz = pts[nb+2] - az;
  float dd = sqrtf(rx*rx + ry*ry + rz*rz + 1e-8f);
  float in7[7] = {ax, ay, az, rx, ry, rz, dd};
  float h16[16];
  #pragma unroll
  for (int j=0;j<16;++j){
    float a = sb1[j];
    #pragma unroll
    for (int c=0;c<7;++c) a += in7[c]*sw1[c*16+j];
    h16[j] = fmaxf(a, 0.f);
  }
  float h32[32];
  #pragma unroll
  for (int j=0;j<32;++j){
    float a = sb2[j];
    #pragma unroll
    for (int c=0;c<16;++c) a += h16[c]*sw2[c*32+j];
    h32[j] = fmaxf(a, 0.f);
  }
  // max-pool over the 16 neighbor lanes (butterfly): all lanes hold the pooled h32
  #pragma unroll
  for (int j=0;j<32;++j){
    h32[j] = fmaxf(h32[j], __shfl_xor(h32[j], 8));
    h32[j] = fmaxf(h32[j], __shfl_xor(h32[j], 4));
    h32[j] = fmaxf(h32[j], __shfl_xor(h32[j], 2));
    h32[j] = fmaxf(h32[j], __shfl_xor(h32[j], 1));
  }
  // cooperative tail: every thread computes lift (cheap, redundant) + 2 output columns
  float lift[32];
  #pragma unroll
  for (int j=0;j<32;++j){
    float a = sbp[j] + ax*swp[0*32+j] + ay*swp[1*32+j] + az*swp[2*32+j];
    lift[j] = fmaxf(a, 0.f);
  }
  #pragma unroll
  for (int jj=0; jj<2; ++jj){
    const int j = k*2 + jj;
    float a = sb3[j];
    #pragma unroll
    for (int c=0;c<32;++c) a += lift[c]*sw3[c*32+j];
    #pragma unroll
    for (int c=0;c<32;++c) a += h32[c]*sw3[(32+c)*32+j];
    ftr1[(size_t)point*32 + j] = fmaxf(a, 0.f);
  }
}

// ------------- column max over N per batch -------------
__global__ __launch_bounds__(256) void colmax_kernel(const float* __restrict__ X, float* __restrict__ out, int J){
  int b  = blockIdx.y;
  int n0 = blockIdx.x * 256;
  int f  = threadIdx.x % J;
  int r0 = threadIdx.x / J;
  int step = 256 / J;
  float vm = 0.f;
  for (int n = n0 + r0; n < n0 + 256; n += step)
    vm = fmaxf(vm, X[((size_t)b*NN + n)*J + f]);
  atomicMax((int*)&out[b*J + f], __float_as_int(vm));
}

// ------- online-softmax pairwise merge -------
__device__ __forceinline__ void omerge(float& m, float& s, float& a, float& f,
                                       float m2, float s2, float a2, float f2){
  float mn = fmaxf(m, m2);
  float e1 = __expf(m - mn), e2 = __expf(m2 - mn);
  s = s*e1 + s2*e2;
  a = a*e1 + a2*e2;
  m = mn;
  f = fmaxf(f, f2);
}

// ---- MFMA residual SMLP: Y = relu( relu(X@wa+ba)@wb + bb + X@ws + bs ) ----
template<int KIN, int JM>
__global__ __launch_bounds__(512) void resblock_mfma(
    const float* __restrict__ s0, int w0,
    const float* __restrict__ s1, int bc1,
    const s16* __restrict__ pwa, const float* __restrict__ ba,
    const s16* __restrict__ pwb, const float* __restrict__ bb,
    const s16* __restrict__ pws, const float* __restrict__ bs,
    float* __restrict__ Y)
{
  constexpr int XP  = KIN + 8;
  constexpr int AP  = JM + 8;
  constexpr int NTB = JM/16;
  constexpr int NTW = NTB/2;
  constexpr int KT1 = KIN/32;
  constexpr int KT2 = JM/32;
  __shared__ s16 xs[64*XP];
  __shared__ s16 as_[64*AP];
  const int tid  = threadIdx.x;
  const int lane = tid & 63;
  const int w    = tid >> 6;
  const int mt   = w >> 1;
  const int half = w & 1;
  const int l15  = lane & 15;
  const int lk   = lane >> 4;
  const int n0   = blockIdx.x * 64;

  for (int t = tid; t < 64*KIN; t += 512){
    int r = t / KIN, c = t - r*KIN;
    int row = n0 + r;
    float v = (c < w0) ? s0[(size_t)row*w0 + c]
                       : s1[(size_t)(bc1 ? (row>>13) : row)*(KIN-w0) + (c-w0)];
    xs[r*XP + c] = (s16)f2bf(v);
  }
  __syncthreads();

  {
    const s16* arow = xs + (mt*16 + l15)*XP + lk*8;
    const int rb = mt*16 + lk*4;
    #pragma unroll
    for (int ntg = 0; ntg < NTW; ++ntg){
      const int ntA = half*NTW + ntg;
      f32x4 acc = {0.f,0.f,0.f,0.f};
      #pragma unroll
      for (int kt = 0; kt < KT1; ++kt){
        short8v a = *(const short8v*)(arow + kt*32);
        short8v bfr = *(const short8v*)(pwa + (((size_t)kt*NTB + ntA)*64 + lane)*8);
        acc = __builtin_amdgcn_mfma_f32_16x16x32_bf16(a, bfr, acc, 0, 0, 0);
      }
      const int col = ntA*16 + l15;
      const float bv = ba[col];
      #pragma unroll
      for (int r=0;r<4;++r)
        as_[(rb+r)*AP + col] = (s16)f2bf(fmaxf(acc[r] + bv, 0.f));
    }
  }
  __syncthreads();

  {
    const s16* arowA = as_ + (mt*16 + l15)*AP + lk*8;
    const s16* arowX = xs  + (mt*16 + l15)*XP + lk*8;
    const int rb = mt*16 + lk*4;
    #pragma unroll
    for (int ntg = 0; ntg < NTW; ++ntg){
      const int ntA = half*NTW + ntg;
      f32x4 acc = {0.f,0.f,0.f,0.f};
      #pragma unroll
      for (int kt = 0; kt < KT2; ++kt){
        short8v a = *(const short8v*)(arowA + kt*32);
        short8v bfr = *(const short8v*)(pwb + (((size_t)kt*NTB + ntA)*64 + lane)*8);
        acc = __builtin_amdgcn_mfma_f32_16x16x32_bf16(a, bfr, acc, 0, 0, 0);
      }
      #pragma unroll
      for (int kt = 0; kt < KT1; ++kt){
        short8v a = *(const short8v*)(arowX + kt*32);
        short8v bfr = *(const short8v*)(pws + (((size_t)kt*NTB + ntA)*64 + lane)*8);
        acc = __builtin_amdgcn_mfma_f32_16x16x32_bf16(a, bfr, acc, 0, 0, 0);
      }
      const int col = ntA*16 + l15;
      const float bv = bb[col] + bs[col];
      #pragma unroll
      for (int r=0;r<4;++r)
        Y[(size_t)(n0 + rb + r)*JM + col] = fmaxf(acc[r] + bv, 0.f);
    }
  }
}

// ---- MFMA fused fuse-GEMM + att-GEMM + online softmax partials ----
__global__ __launch_bounds__(512) void fuseatt_mfma(
    const float* __restrict__ f1, const float* __restrict__ f2,
    const float* __restrict__ f3, const float* __restrict__ g3,
    const s16* __restrict__ pfw, const float* __restrict__ fb,
    const s16* __restrict__ paw, const float* __restrict__ ab,
    float4* __restrict__ part)
{
  __shared__ __align__(16) char arena[112640];
  s16*   f4s = (s16*)arena;                 // [64][520] bf16 ftr4 tile
  s16*   xs  = (s16*)(arena + 66560);       // [64][360] bf16 input tile
  float4* pb = (float4*)(arena + 66560);    // [4 mt][512 col] partials (aliases xs)
  const int chunk = blockIdx.x;
  const int tid  = threadIdx.x;
  const int lane = tid & 63;
  const int w    = tid >> 6;
  const int mt   = w >> 1;
  const int half = w & 1;
  const int l15  = lane & 15;
  const int lk   = lane >> 4;
  const int n0   = chunk*64;

  for (int t = tid; t < 64*352; t += 512){
    int r = t / 352, c = t - r*352;
    int row = n0 + r;
    float v;
    if (c < 32)       v = f1[(size_t)row*32 + c];
    else if (c < 96)  v = f2[(size_t)row*64 + (c-32)];
    else if (c < 224) v = f3[(size_t)row*128 + (c-96)];
    else              v = g3[(size_t)(row>>13)*128 + (c-224)];
    xs[r*360 + c] = (s16)f2bf(v);
  }
  __syncthreads();

  {
    const s16* arow = xs + (mt*16 + l15)*360 + lk*8;
    const int rb = mt*16 + lk*4;
    for (int ntg = 0; ntg < 16; ntg += 4){
      const int ntA = half*16 + ntg;
      f32x4 acc0={0,0,0,0}, acc1={0,0,0,0}, acc2={0,0,0,0}, acc3={0,0,0,0};
      for (int kt = 0; kt < 11; ++kt){
        short8v a = *(const short8v*)(arow + kt*32);
        const s16* bp = pfw + (((size_t)kt*32 + ntA)*64 + lane)*8;
        short8v b0 = *(const short8v*)(bp);
        short8v b1 = *(const short8v*)(bp + 512);
        short8v b2 = *(const short8v*)(bp + 1024);
        short8v b3 = *(const short8v*)(bp + 1536);
        acc0 = __builtin_amdgcn_mfma_f32_16x16x32_bf16(a, b0, acc0, 0, 0, 0);
        acc1 = __builtin_amdgcn_mfma_f32_16x16x32_bf16(a, b1, acc1, 0, 0, 0);
        acc2 = __builtin_amdgcn_mfma_f32_16x16x32_bf16(a, b2, acc2, 0, 0, 0);
        acc3 = __builtin_amdgcn_mfma_f32_16x16x32_bf16(a, b3, acc3, 0, 0, 0);
      }
      #define FUSE_EPI(ACC, J) { \
        int col = (ntA + (J))*16 + l15; float bv = fb[col]; \
        f4s[(rb+0)*520 + col] = (s16)f2bf(fmaxf(ACC[0] + bv, 0.f)); \
        f4s[(rb+1)*520 + col] = (s16)f2bf(fmaxf(ACC[1] + bv, 0.f)); \
        f4s[(rb+2)*520 + col] = (s16)f2bf(fmaxf(ACC[2] + bv, 0.f)); \
        f4s[(rb+3)*520 + col] = (s16)f2bf(fmaxf(ACC[3] + bv, 0.f)); }
      FUSE_EPI(acc0, 0) FUSE_EPI(acc1, 1) FUSE_EPI(acc2, 2) FUSE_EPI(acc3, 3)
      #undef FUSE_EPI
    }
  }
  __syncthreads();

  {
    const s16* arow = f4s + (mt*16 + l15)*520 + lk*8;
    const int rb = mt*16 + lk*4;
    for (int ntg = 0; ntg < 16; ntg += 4){
      const int ntA = half*16 + ntg;
      f32x4 acc0={0,0,0,0}, acc1={0,0,0,0}, acc2={0,0,0,0}, acc3={0,0,0,0};
      for (int kt = 0; kt < 16; ++kt){
        short8v a = *(const short8v*)(arow + kt*32);
        const s16* bp = paw + (((size_t)kt*32 + ntA)*64 + lane)*8;
        short8v b0 = *(const short8v*)(bp);
        short8v b1 = *(const short8v*)(bp + 512);
        short8v b2 = *(const short8v*)(bp + 1024);
        short8v b3 = *(const short8v*)(bp + 1536);
        acc0 = __builtin_amdgcn_mfma_f32_16x16x32_bf16(a, b0, acc0, 0, 0, 0);
        acc1 = __builtin_amdgcn_mfma_f32_16x16x32_bf16(a, b1, acc1, 0, 0, 0);
        acc2 = __builtin_amdgcn_mfma_f32_16x16x32_bf16(a, b2, acc2, 0, 0, 0);
        acc3 = __builtin_amdgcn_mfma_f32_16x16x32_bf16(a, b3, acc3, 0, 0, 0);
      }
      #define ATT_EPI(ACC, J) { \
        int col = (ntA + (J))*16 + l15; float lb = ab[col]; \
        float m_ = -INFINITY, s_ = 0.f, a_ = 0.f, fx_ = 0.f; \
        _Pragma("unroll") \
        for (int r = 0; r < 4; ++r){ \
          float lv = ACC[r] + lb; \
          float x  = bf2f((unsigned short)f4s[(rb+r)*520 + col]); \
          float mn = fmaxf(m_, lv); \
          float e0 = __expf(m_ - mn), e1 = __expf(lv - mn); \
          s_ = s_*e0 + e1; a_ = a_*e0 + x*e1; m_ = mn; fx_ = fmaxf(fx_, x); \
        } \
        { float om = __shfl_xor(m_,16), os = __shfl_xor(s_,16), oa = __shfl_xor(a_,16), of = __shfl_xor(fx_,16); \
          omerge(m_, s_, a_, fx_, om, os, oa, of); } \
        { float om = __shfl_xor(m_,32), os = __shfl_xor(s_,32), oa = __shfl_xor(a_,32), of = __shfl_xor(fx_,32); \
          omerge(m_, s_, a_, fx_, om, os, oa, of); } \
        if (lk == 0) pb[mt*512 + col] = make_float4(m_, s_, a_, fx_); }
      ATT_EPI(acc0, 0) ATT_EPI(acc1, 1) ATT_EPI(acc2, 2) ATT_EPI(acc3, 3)
      #undef ATT_EPI
    }
  }
  __syncthreads();

  {
    float4 p0 = pb[tid], p1 = pb[512 + tid], p2 = pb[1024 + tid], p3 = pb[1536 + tid];
    float m_ = p0.x, s_ = p0.y, a_ = p0.z, f_ = p0.w;
    omerge(m_, s_, a_, f_, p1.x, p1.y, p1.z, p1.w);
    omerge(m_, s_, a_, f_, p2.x, p2.y, p2.z, p2.w);
    omerge(m_, s_, a_, f_, p3.x, p3.y, p3.z, p3.w);
    part[(size_t)chunk*512 + tid] = make_float4(m_, s_, a_, f_);
  }
}

// ---- two-stage attention merge ----
__global__ __launch_bounds__(512) void attmerge1_kernel(const float4* __restrict__ part, float4* __restrict__ part2){
  int g = blockIdx.x;
  int b = blockIdx.y;
  int f = threadIdx.x;
  float m=-INFINITY, s=0.f, a=0.f, fx=0.f;
  for (int c = g*8; c < g*8+8; ++c){
    float4 p = part[((size_t)(b*128 + c))*512 + f];
    omerge(m, s, a, fx, p.x, p.y, p.z, p.w);
  }
  part2[((size_t)(b*16 + g))*512 + f] = make_float4(m, s, a, fx);
}

__global__ __launch_bounds__(256) void attmerge2_kernel(const float4* __restrict__ part2, float* __restrict__ feat){
  int t = blockIdx.x*256 + threadIdx.x;
  if (t >= BB*512) return;
  int b = t >> 9, f = t & 511;
  float m=-INFINITY, s=0.f, a=0.f, fx=0.f;
  for (int c=0;c<16;++c){
    float4 p = part2[((size_t)(b*16 + c))*512 + f];
    omerge(m, s, a, fx, p.x, p.y, p.z, p.w);
  }
  feat[(size_t)b*1024 + f] = fx;
  feat[(size_t)b*1024 + 512 + f] = a / s;
}

// ------------- head MLP: split-K atomic partials (Y pre-initialized with bias in prep) -------------
__global__ __launch_bounds__(256) void headpart_kernel(
    const float* __restrict__ X, const float* __restrict__ W, float* __restrict__ Y,
    int K, int J, int relu_in)
{
  const int j  = blockIdx.x*64 + (threadIdx.x & 63);
  const int k0 = blockIdx.y*128 + (threadIdx.x >> 6)*32;
  float acc0 = 0.f, acc1 = 0.f;
  #pragma unroll 8
  for (int k = 0; k < 32; ++k){
    float x0 = X[k0+k], x1 = X[K + k0+k];
    if (relu_in){ x0 = fmaxf(x0, 0.f); x1 = fmaxf(x1, 0.f); }
    float w = W[(size_t)(k0+k)*J + j];
    acc0 += x0*w; acc1 += x1*w;
  }
  atomicAdd(&Y[j], acc0);
  atomicAdd(&Y[J+j], acc1);
}

extern "C" void kernel_launch(void* const* d_in, const int* in_sizes, int n_in,
                              void* d_out, int out_size, void* d_ws, size_t ws_size,
                              hipStream_t stream)
{
  const float* pts    = (const float*)d_in[0];
  const float* na1w1  = (const float*)d_in[1];
  const float* na1b1  = (const float*)d_in[2];
  const float* na1w2  = (const float*)d_in[3];
  const float* na1b2  = (const float*)d_in[4];
  const float* na2w   = (const float*)d_in[5];
  const float* na2b   = (const float*)d_in[6];
  const float* na3w   = (const float*)d_in[7];
  const float* na3b   = (const float*)d_in[8];
  const float* r1aw   = (const float*)d_in[9];
  const float* r1ab   = (const float*)d_in[10];
  const float* r1bw   = (const float*)d_in[11];
  const float* r1bb   = (const float*)d_in[12];
  const float* r1sw   = (const float*)d_in[13];
  const float* r1sb   = (const float*)d_in[14];
  const float* r2aw   = (const float*)d_in[15];
  const float* r2ab   = (const float*)d_in[16];
  const float* r2bw   = (const float*)d_in[17];
  const float* r2bb   = (const float*)d_in[18];
  const float* r2sw   = (const float*)d_in[19];
  const float* r2sb   = (const float*)d_in[20];
  const float* fusew  = (const float*)d_in[21];
  const float* fuseb  = (const float*)d_in[22];
  const float* attw   = (const float*)d_in[23];
  const float* attb   = (const float*)d_in[24];
  const float* fc1w   = (const float*)d_in[25];
  const float* fc1b   = (const float*)d_in[26];
  const float* fc2w   = (const float*)d_in[27];
  const float* fc2b   = (const float*)d_in[28];
  const float* fc3w   = (const float*)d_in[29];
  const float* fc3b   = (const float*)d_in[30];

  if (n_in < 31) return;
  if (in_sizes[0] != NPTS*3) return;
  if (in_sizes[21] != 352*512) return;
  if (in_sizes[29] != 1024*1024) return;

  // Workspace layout (float offsets).
  const size_t o_ftr1 = 0;
  const size_t o_ftr2 = 524288;
  const size_t o_ftr3 = 1572864;
  const size_t o_knn  = 1572864;
  const size_t o_part = 3670016;
  const size_t o_g2   = 4194304;
  const size_t o_g3   = 4194432;
  const size_t o_feat = 4194688;
  const size_t o_h1   = 4196736;
  const size_t o_h2   = 4197760;
  const size_t o_pfw  = 4199808;
  const size_t o_paw  = o_pfw + 90112;
  const size_t mfma_bytes = 4420992ull * 4ull;
  if (ws_size < mfma_bytes) return;

  float* ws = (float*)d_ws;
  float*  ftr1  = ws + o_ftr1;
  float4* pts4  = (float4*)(ws + o_ftr1);
  float4* part2 = (float4*)(ws + o_ftr1);
  float*  ftr2 = ws + o_ftr2;
  float*  ftr3 = ws + o_ftr3;
  int*    knn  = (int*)(ws + o_knn);
  float4* part = (float4*)(ws + o_part);
  float*  g2   = ws + o_g2;
  float*  g3   = ws + o_g3;
  float*  feat = ws + o_feat;
  float*  h1   = ws + o_h1;
  float*  h2   = ws + o_h2;
  s16*    pfw  = (s16*)(ws + o_pfw);
  s16*    paw  = (s16*)(ws + o_paw);
  s16*    pr1a = (s16*)(ws + o_part);
  s16*    pr1b = pr1a + 2048;
  s16*    pr1s = pr1b + 4096;
  s16*    pr2a = pr1s + 2048;
  s16*    pr2b = pr2a + 16384;
  s16*    pr2s = pr2b + 16384;

  // 1. fused prep
  prep_kernel<<<1318, 64, 0, stream>>>(fusew, pfw, attw, paw,
                                       r1aw, pr1a, r1bw, pr1b, r1sw, pr1s,
                                       r2aw, pr2a, r2bw, pr2b, r2sw, pr2s,
                                       pts, pts4, g2,
                                       fc1b, h1, fc2b, h2, fc3b, (float*)d_out);
  // 2. main pipeline
  knn_kernel<<<NPTS, 256, 0, stream>>>(pts, pts4, knn);
  nbr_kernel<<<NPTS*16/256, 256, 0, stream>>>(pts, knn, na1w1, na1b1, na1w2, na1b2,
                                              na2w, na2b, na3w, na3b, ftr1);
  resblock_mfma<32,64><<<NPTS/64, 512, 0, stream>>>(ftr1, 32, nullptr, 0,
                                                    pr1a, r1ab, pr1b, r1bb, pr1s, r1sb, ftr2);
  colmax_kernel<<<dim3(32,2), 256, 0, stream>>>(ftr2, g2, 64);
  resblock_mfma<128,128><<<NPTS/64, 512, 0, stream>>>(ftr2, 64, g2, 1,
                                                      pr2a, r2ab, pr2b, r2bb, pr2s, r2sb, ftr3);
  colmax_kernel<<<dim3(32,2), 256, 0, stream>>>(ftr3, g3, 128);
  fuseatt_mfma<<<NPTS/64, 512, 0, stream>>>(ftr1, ftr2, ftr3, g3,
                                            pfw, fuseb, paw, attb, part);
  attmerge1_kernel<<<dim3(16,2), 512, 0, stream>>>(part, part2);
  attmerge2_kernel<<<4, 256, 0, stream>>>(part2, feat);
  headpart_kernel<<<dim3(8, 8),  256, 0, stream>>>(feat, fc1w, h1, 1024, 512, 0);
  headpart_kernel<<<dim3(16, 4), 256, 0, stream>>>(h1, fc2w, h2, 512, 1024, 1);
  headpart_kernel<<<dim3(16, 8), 256, 0, stream>>>(h2, fc3w, (float*)d_out, 1024, 1024, 1);
}